// Round 9
// baseline (184.913 us; speedup 1.0000x reference)
//
#include <hip/hip_runtime.h>
#include <math.h>

// Converse2D on gfx950 — spectral restructuring (R12):
//   out(2y+u, 2x+v) plane = ifft136( A_uv[g] * Xhat[g] ), per (n,c,u,v)
//   Xhat = rfft136x136(wrap_pad(x)); A_uv = per-channel multiplier (Hermitian).
// R12 (vs R11): two conv cuts (prep f32 kept; residual ~73us shown to be
// harness-side, conv is the only handle):
//   - RSC4 70 -> 73: row stride 292 dwords == 4 mod 32 (was 24 mod 32, which
//     cycled through only 4 bank positions -> measured 6.27M conflict cycles
//     ~= 10us). 8 consecutive lanes now tile all 32 banks for b128.
//     Fwd twiddle tables dropped (conjugate inverse tables at use,
//     compile-time) to fit LDS: 136*73*16 + 306*8 = 161,296 B.
//   - fwd cols-stage-2 computes into REGISTERS (Xk[17], static idx), then
//     S = A*X writes straight to z4 natural layout for u=0 and replays from
//     regs for u=1. Removes the X write-back, the 9384-read Xcap phase, and a
//     barrier. VGPR watch: WRITE_SIZE jump = spill = revert (R9 lesson).

#define MDIM 136
#define RSCF 146            // fwd float2 view: row stride (float2 units) = 2*RSC4
#define RSC4 73             // inverse float4 view: row stride (float4 units)
#define HC   69             // stored Hermitian half columns (0..68)
#define PLANE_HALF (MDIM*HC)   // 9384 per plane
#define NPLANES 256         // N*C
#define LDS_BYTES (MDIM*RSC4*16 + 306*8)   // plane + lutI/tI136/tI68 = 161,296 B
#define PI_D 3.14159265358979323846
#define NTH 1024

__device__ __forceinline__ int slot136(int k) { return 17*(k & 7) + (k >> 3); }
__device__ __forceinline__ int slot68(int k)  { return 17*(k & 3) + (k >> 2); }

// ---------- float4 "dual-complex" helpers: q = (re0, im0, re1, im1) ----------
__device__ __forceinline__ float4 q_add(float4 a, float4 b)
{ return make_float4(a.x+b.x, a.y+b.y, a.z+b.z, a.w+b.w); }
__device__ __forceinline__ float4 q_sub(float4 a, float4 b)
{ return make_float4(a.x-b.x, a.y-b.y, a.z-b.z, a.w-b.w); }
__device__ __forceinline__ float4 q_muli(float4 a, float d)   // d * (i*a), both halves
{ return make_float4(-d*a.y, d*a.x, -d*a.w, d*a.z); }
__device__ __forceinline__ float4 q_scale(float4 a, float s)
{ return make_float4(s*a.x, s*a.y, s*a.z, s*a.w); }
__device__ __forceinline__ float4 q_fma(float4 a, float s, float4 acc)
{ return make_float4(fmaf(a.x,s,acc.x), fmaf(a.y,s,acc.y),
                     fmaf(a.z,s,acc.z), fmaf(a.w,s,acc.w)); }
__device__ __forceinline__ float4 cmul4(float4 q, float2 w)   // same twiddle, both halves
{ return make_float4(q.x*w.x - q.y*w.y, q.x*w.y + q.y*w.x,
                     q.z*w.x - q.w*w.y, q.z*w.y + q.w*w.x); }

// ---------- symmetric 17-point DFT (float2, fwd), strided, sink outputs ----------
template<int DIR, class F>
__device__ __forceinline__ void dft17_sink(float2* z, int base, int stride, F f)
{
    constexpr float C17[9] = {1.f, 0.93247223f, 0.73900892f, 0.44573836f,
                              0.09226836f, -0.27366299f, -0.60263464f,
                              -0.85021714f, -0.98297310f};
    constexpr float S17[9] = {0.f, 0.36124167f, 0.67369564f, 0.89516329f,
                              0.99573418f, 0.96182564f, 0.79801723f,
                              0.52643216f, 0.18374952f};
    constexpr float d = (DIR > 0) ? 1.f : -1.f;
    float xr[17], xi[17];
#pragma unroll
    for (int n = 0; n < 17; n++) {
        float2 v = z[base + n*stride];
        xr[n] = v.x; xi[n] = v.y;
    }
    float ar[8], ai[8], br[8], bi[8];
#pragma unroll
    for (int n = 1; n <= 8; n++) {
        ar[n-1] = xr[n] + xr[17-n];  ai[n-1] = xi[n] + xi[17-n];
        br[n-1] = xr[n] - xr[17-n];  bi[n-1] = xi[n] - xi[17-n];
    }
    float s0r = xr[0], s0i = xi[0];
#pragma unroll
    for (int n = 0; n < 8; n++) { s0r += ar[n]; s0i += ai[n]; }
    f(0, s0r, s0i);
#pragma unroll
    for (int k = 1; k <= 8; k++) {
        float Pr = xr[0], Pi = xi[0], Qr = 0.f, Qi = 0.f;
#pragma unroll
        for (int n = 1; n <= 8; n++) {
            int m = (k*n) % 17;
            float cc = (m <= 8) ? C17[m] : C17[17-m];
            float ss = (m <= 8) ? S17[m] : -S17[17-m];
            Pr = fmaf(ar[n-1], cc, Pr);
            Pi = fmaf(ai[n-1], cc, Pi);
            Qr = fmaf(br[n-1], ss, Qr);
            Qi = fmaf(bi[n-1], ss, Qi);
        }
        f(k,    Pr - d*Qi, Pi + d*Qr);
        f(17-k, Pr + d*Qi, Pi - d*Qr);
    }
}

// ---------- symmetric 17-point DFT (float4 dual-plane), strided, in-place ----------
template<int DIR>
__device__ __forceinline__ void dft17q(float4* z, int base, int stride)
{
    constexpr float C17[9] = {1.f, 0.93247223f, 0.73900892f, 0.44573836f,
                              0.09226836f, -0.27366299f, -0.60263464f,
                              -0.85021714f, -0.98297310f};
    constexpr float S17[9] = {0.f, 0.36124167f, 0.67369564f, 0.89516329f,
                              0.99573418f, 0.96182564f, 0.79801723f,
                              0.52643216f, 0.18374952f};
    constexpr float d = (DIR > 0) ? 1.f : -1.f;
    float4 x0 = z[base];
    float4 a[8], b[8];
#pragma unroll
    for (int n = 1; n <= 8; n++) {
        float4 u = z[base + n*stride];
        float4 v = z[base + (17-n)*stride];
        a[n-1] = q_add(u, v);
        b[n-1] = q_sub(u, v);
    }
    float4 s0 = x0;
#pragma unroll
    for (int n = 0; n < 8; n++) s0 = q_add(s0, a[n]);
    z[base] = s0;
#pragma unroll
    for (int k = 1; k <= 8; k++) {
        float4 P = x0, Q = make_float4(0.f,0.f,0.f,0.f);
#pragma unroll
        for (int n = 1; n <= 8; n++) {
            int m = (k*n) % 17;
            float cc = (m <= 8) ? C17[m] : C17[17-m];
            float ss = (m <= 8) ? S17[m] : -S17[17-m];
            P = q_fma(a[n-1], cc, P);
            Q = q_fma(b[n-1], ss, Q);
        }
        float4 iq = q_muli(Q, d);
        z[base + k*stride]      = q_add(P, iq);
        z[base + (17-k)*stride] = q_sub(P, iq);
    }
}

// ---------- radix-4 + table twiddle (float2; tables are INVERSE-dir, DIR<0 conj) ----------
template<int DIR>
__device__ __forceinline__ void radix4_tw(float2* z, const float2* t68, int base, int n2,
                                          float2 Z0, float2 Z1, float2 Z2, float2 Z3)
{
    constexpr float d = (DIR > 0) ? 1.0f : -1.0f;
    float t0r = Z0.x+Z2.x, t0i = Z0.y+Z2.y;
    float t1r = Z0.x-Z2.x, t1i = Z0.y-Z2.y;
    float t2r = Z1.x+Z3.x, t2i = Z1.y+Z3.y;
    float t3r = Z1.x-Z3.x, t3i = Z1.y-Z3.y;
    float X0r = t0r+t2r,     X0i = t0i+t2i;
    float X2r = t0r-t2r,     X2i = t0i-t2i;
    float X1r = t1r - d*t3i, X1i = t1i + d*t3r;
    float X3r = t1r + d*t3i, X3i = t1i - d*t3r;
    z[base + n2] = make_float2(X0r, X0i);
    float2 w1 = t68[n2], w2 = t68[17 + n2], w3 = t68[34 + n2];
    if (DIR < 0) { w1.y = -w1.y; w2.y = -w2.y; w3.y = -w3.y; }
    z[base + 17 + n2] = make_float2(X1r*w1.x - X1i*w1.y, X1r*w1.y + X1i*w1.x);
    z[base + 34 + n2] = make_float2(X2r*w2.x - X2i*w2.y, X2r*w2.y + X2i*w2.x);
    z[base + 51 + n2] = make_float2(X3r*w3.x - X3i*w3.y, X3r*w3.y + X3i*w3.x);
}

// ---------- radix-4 + table twiddle (float4 dual-plane, inverse only) ----------
template<int DIR>
__device__ __forceinline__ void radix4q_tw(float4* z, const float2* t68, int base, int n2,
                                           float4 Z0, float4 Z1, float4 Z2, float4 Z3)
{
    constexpr float d = (DIR > 0) ? 1.0f : -1.0f;
    float4 t0 = q_add(Z0, Z2), t1 = q_sub(Z0, Z2);
    float4 t2 = q_add(Z1, Z3), t3 = q_sub(Z1, Z3);
    float4 X0 = q_add(t0, t2), X2 = q_sub(t0, t2);
    float4 it3 = q_muli(t3, d);
    float4 X1 = q_add(t1, it3), X3 = q_sub(t1, it3);
    z[base + n2] = X0;
    float2 w1 = t68[n2], w2 = t68[17 + n2], w3 = t68[34 + n2];
    z[base + 17 + n2] = cmul4(X1, w1);
    z[base + 34 + n2] = cmul4(X2, w2);
    z[base + 51 + n2] = cmul4(X3, w3);
}

// ---------- 136-pt CT stage 1 (radix-8 + table twiddle), float2 fwd ----------
template<int DIR>
__device__ __forceinline__ void fft136_s1_body(float2* z, const float2* t136,
                                               int c, int n2)
{
    constexpr float d = (DIR > 0) ? 1.0f : -1.0f;
    constexpr float C707 = 0.70710678118654752f;
    float xr[8], xi[8];
#pragma unroll
    for (int n1 = 0; n1 < 8; n1++) {
        float2 v = z[(17*n1 + n2)*RSCF + c];
        xr[n1] = v.x; xi[n1] = v.y;
    }
    float e0r = xr[0]+xr[4], e0i = xi[0]+xi[4];
    float e1r = xr[0]-xr[4], e1i = xi[0]-xi[4];
    float o0r = xr[2]+xr[6], o0i = xi[2]+xi[6];
    float o1r = xr[2]-xr[6], o1i = xi[2]-xi[6];
    float E0r = e0r+o0r, E0i = e0i+o0i;
    float E2r = e0r-o0r, E2i = e0i-o0i;
    float E1r = e1r - d*o1i, E1i = e1i + d*o1r;
    float E3r = e1r + d*o1i, E3i = e1i - d*o1r;
    float f0r = xr[1]+xr[5], f0i = xi[1]+xi[5];
    float f1r = xr[1]-xr[5], f1i = xi[1]-xi[5];
    float h0r = xr[3]+xr[7], h0i = xi[3]+xi[7];
    float h1r = xr[3]-xr[7], h1i = xi[3]-xi[7];
    float O0r = f0r+h0r, O0i = f0i+h0i;
    float O2r = f0r-h0r, O2i = f0i-h0i;
    float O1r = f1r - d*h1i, O1i = f1i + d*h1r;
    float O3r = f1r + d*h1i, O3i = f1i - d*h1r;
    float t1r =  C707*(O1r - d*O1i), t1i = C707*(O1i + d*O1r);
    float t2r = -d*O2i,              t2i = d*O2r;
    float t3r = -C707*(O3r + d*O3i), t3i = C707*(d*O3r - O3i);
    float Xr[8], Xi[8];
    Xr[0]=E0r+O0r; Xi[0]=E0i+O0i;  Xr[4]=E0r-O0r; Xi[4]=E0i-O0i;
    Xr[1]=E1r+t1r; Xi[1]=E1i+t1i;  Xr[5]=E1r-t1r; Xi[5]=E1i-t1i;
    Xr[2]=E2r+t2r; Xi[2]=E2i+t2i;  Xr[6]=E2r-t2r; Xi[6]=E2i-t2i;
    Xr[3]=E3r+t3r; Xi[3]=E3i+t3i;  Xr[7]=E3r-t3r; Xi[7]=E3i-t3i;
    z[n2*RSCF + c] = make_float2(Xr[0], Xi[0]);
#pragma unroll
    for (int k1 = 1; k1 < 8; k1++) {
        float2 w = t136[(k1-1)*17 + n2];
        if (DIR < 0) w.y = -w.y;
        z[(17*k1 + n2)*RSCF + c] = make_float2(Xr[k1]*w.x - Xi[k1]*w.y,
                                               Xr[k1]*w.y + Xi[k1]*w.x);
    }
}

// ---------- 136-pt CT stage 1 (radix-8 + table twiddle), float4 dual-plane ----------
template<int DIR>
__device__ __forceinline__ void fft136q_s1_body(float4* z, const float2* t136,
                                                int c, int n2)
{
    constexpr float d = (DIR > 0) ? 1.0f : -1.0f;
    constexpr float C707 = 0.70710678118654752f;
    float4 x[8];
#pragma unroll
    for (int n1 = 0; n1 < 8; n1++) x[n1] = z[(17*n1 + n2)*RSC4 + c];
    float4 e0 = q_add(x[0], x[4]), e1 = q_sub(x[0], x[4]);
    float4 o0 = q_add(x[2], x[6]), o1 = q_sub(x[2], x[6]);
    float4 E0 = q_add(e0, o0), E2 = q_sub(e0, o0);
    float4 io1 = q_muli(o1, d);
    float4 E1 = q_add(e1, io1), E3 = q_sub(e1, io1);
    float4 f0 = q_add(x[1], x[5]), f1 = q_sub(x[1], x[5]);
    float4 h0 = q_add(x[3], x[7]), h1 = q_sub(x[3], x[7]);
    float4 O0 = q_add(f0, h0), O2 = q_sub(f0, h0);
    float4 ih1 = q_muli(h1, d);
    float4 O1 = q_add(f1, ih1), O3 = q_sub(f1, ih1);
    float4 t1 = q_scale(q_add(O1, q_muli(O1, d)), C707);
    float4 t2 = q_muli(O2, d);
    float4 t3 = q_scale(q_sub(O3, q_muli(O3, d)), -C707);
    float4 X0 = q_add(E0, O0), X4 = q_sub(E0, O0);
    float4 X1 = q_add(E1, t1), X5 = q_sub(E1, t1);
    float4 X2 = q_add(E2, t2), X6 = q_sub(E2, t2);
    float4 X3 = q_add(E3, t3), X7 = q_sub(E3, t3);
    z[n2*RSC4 + c] = X0;
    z[(17*1 + n2)*RSC4 + c] = cmul4(X1, t136[0*17 + n2]);
    z[(17*2 + n2)*RSC4 + c] = cmul4(X2, t136[1*17 + n2]);
    z[(17*3 + n2)*RSC4 + c] = cmul4(X3, t136[2*17 + n2]);
    z[(17*4 + n2)*RSC4 + c] = cmul4(X4, t136[3*17 + n2]);
    z[(17*5 + n2)*RSC4 + c] = cmul4(X5, t136[4*17 + n2]);
    z[(17*6 + n2)*RSC4 + c] = cmul4(X6, t136[5*17 + n2]);
    z[(17*7 + n2)*RSC4 + c] = cmul4(X7, t136[6*17 + n2]);
}

// c2r pack (float4 dual-plane), same w both halves.
__device__ __forceinline__ float4 c2r_pack4(float4 a, float4 b, float2 w)
{
    float Sx = a.x + b.x, Sy = a.y - b.y;
    float Dx = a.x - b.x, Dy = a.y + b.y;
    float Ox = w.x*Dx - w.y*Dy, Oy = w.x*Dy + w.y*Dx;
    float Sz = a.z + b.z, Sw = a.w - b.w;
    float Dz = a.z - b.z, Dw = a.w + b.w;
    float Oz = w.x*Dz - w.y*Dw, Ow = w.x*Dw + w.y*Dz;
    return make_float4(Sx - Oy, Sy + Ox, Sz - Ow, Sw + Oz);
}

// ---------- Fused forward + inverse: one WG per (n,c) plane (256 WGs) ----------
__global__ __launch_bounds__(1024, 4) void conv_kernel(const float* __restrict__ x,
                                                       const float4* __restrict__ Abuf,
                                                       float* __restrict__ out)
{
    extern __shared__ float4 z4s[];
    float4* z4    = z4s;                      // inverse: [136][73] dual-plane
    float2* zf    = (float2*)z4s;             // fwd view: row stride 146, cols 0..68
    float2* lutI  = (float2*)(z4s + MDIM*RSC4);   // exp(+2*pi*i*t/136)
    float2* tI136 = lutI + MDIM;              // [7][17]: w136^(k1*n2), inverse dir
    float2* tI68  = tI136 + 119;              // [3][17]: w68^((j+1)*n2), inverse dir
    const int tid = threadIdx.x;
    const int nc  = blockIdx.x;               // n*64 + c
    const int c   = nc & 63;

    if (tid < MDIM) {
        float s, cc; sincosf(2.0f*(float)PI_D*(float)tid/136.0f, &s, &cc);
        lutI[tid] = make_float2(cc, s);
    } else if (tid < MDIM + 119) {
        int it = tid - MDIM;
        int k1 = it/17 + 1, n2 = it - (it/17)*17;
        float s, cc; sincosf((float)(PI_D/68.0)*(float)(k1*n2), &s, &cc);
        tI136[it] = make_float2(cc, s);
    } else if (tid < MDIM + 119 + 51) {
        int it = tid - MDIM - 119;
        int j = it/17, n2 = it - 17*j;
        float s, cc; sincosf((float)(PI_D/34.0)*(float)((j+1)*n2), &s, &cc);
        tI68[it] = make_float2(cc, s);
    }
    // ---------------- forward on zf (stride RSCF) ----------------
    const float* xp = x + (size_t)nc * (128*128);
    {   // packed-row load: zf[i][n] = xp(i,2n) + i*xp(i,2n+1), wrap pad by 4
        int i = tid / 68, n = tid - (tid/68)*68;
        for (int e = tid; e < MDIM*68; e += NTH) {
            int si = (i + 124) & 127;
            int j0 = (2*n + 124) & 127;              // always even, pair never wraps
            zf[i*RSCF + n] = *reinterpret_cast<const float2*>(xp + si*128 + j0);
            i += 15; n += 4; if (n >= 68) { n -= 68; i++; }
        }
    }
    __syncthreads();
    {   // rows stage 1 (radix-4)
        int row = tid / 17;
        int n2  = tid - row*17;
        for (int e = tid; e < MDIM*17; e += NTH) {
            int base = row*RSCF;
            float2 Z0 = zf[base + n2];
            float2 Z1 = zf[base + 17 + n2];
            float2 Z2 = zf[base + 34 + n2];
            float2 Z3 = zf[base + 51 + n2];
            radix4_tw<-1>(zf, tI68, base, n2, Z0, Z1, Z2, Z3);
            row += 60; n2 += 4; if (n2 >= 17) { n2 -= 17; row++; }
        }
    }
    __syncthreads();
    if (tid < MDIM*4) {                              // rows stage 2: Z[k] at slot68(k)
        int row = tid >> 2, k1 = tid & 3;
        int base = row*RSCF + 17*k1;
        dft17_sink<-1>(zf, base, 1, [&](int k2, float re, float im) {
            zf[base + k2] = make_float2(re, im);
        });
    }
    __syncthreads();
    {   // r2c unpack: item k handles (k, 68-k), in-place at slots
        int row = tid / 35, k = tid - (tid/35)*35;
        for (int e = tid; e < MDIM*35; e += NTH) {
            int base = row*RSCF;
            int sa = slot68(k);
            float2 Za = zf[base+sa];
            float Zar = Za.x, Zai = Za.y;
            float Zbr, Zbi; int sb;
            if (k == 0) { Zbr = Zar; Zbi = Zai; sb = 68; }  // Z[68]==Z[0]; X[68]->col 68
            else {
                int kk = 68-k; sb = slot68(kk);
                float2 Zb = zf[base+sb]; Zbr = Zb.x; Zbi = Zb.y;
            }
            float2 w = lutI[k];                             // conj -> fwd w136^k
            float wc = w.x, ws = -w.y;
            float Er = 0.5f*(Zar + Zbr), Ei = 0.5f*(Zai - Zbi);
            float Dr = 0.5f*(Zar - Zbr), Di = 0.5f*(Zai + Zbi);
            float Tr = wc*Dr - ws*Di, Ti = wc*Di + ws*Dr;   // w^k * D
            zf[base+sa] = make_float2(Er + Ti, Ei - Tr);    // X[k] = E - i*(w^k D)
            float E2r = Er,  E2i = -Ei;
            float D2r = -Dr, D2i = Di;
            float w2c = -wc, w2s = ws;                      // w136^(68-k) = -conj(w^k)
            float T2r = w2c*D2r - w2s*D2i, T2i = w2c*D2i + w2s*D2r;
            zf[base+sb] = make_float2(E2r + T2i, E2i - T2r); // X[68-k]
            row += 29; k += 9; if (k >= 35) { k -= 35; row++; }
        }
    }
    __syncthreads();
    for (int e = tid; e < HC*17; e += NTH) {         // columns stage 1 (69 cols)
        int cc = (e*241) >> 12;                      // e/17, e <= 1172
        int n2 = e - cc*17;
        fft136_s1_body<-1>(zf, tI136, cc, n2);
    }
    __syncthreads();
    // Columns stage 2 into REGISTERS (no LDS write-back): thread (cS,k1S) holds
    // X[k1S+8*k2] of natural column g2n for k2=0..16. Static Xk indices (sink
    // k2 is unroll-constant).
    float2 Xk[17];
    int g2n = 0, k1S = 0;
    if (tid < HC*8) {
        int cS = tid >> 3; k1S = tid & 7;
        int cd = (cS*241) >> 12;                     // cS/17
        int cm = cS - 17*cd;
        g2n = (cS == 68) ? 68 : (4*cm + cd);         // natural g2 of this column
        dft17_sink<-1>(zf, 17*k1S*RSCF + cS, RSCF, [&](int k2, float re, float im) {
            Xk[k2] = make_float2(re, im);
        });
    }
    __syncthreads();                                 // all zf reads done
    // ---------------- inverse, u = 0,1; both v-planes in z4 ----------------
    float* op = out + (size_t)nc * (256*256);
#pragma unroll 1
    for (int u = 0; u < 2; u++) {
        // S = A_uv * Xhat (both v), written straight to natural [g1][g2n].
        if (tid < HC*8) {
            const float4* Ag = Abuf + (size_t)(c*2 + u) * PLANE_HALF + g2n;
#pragma unroll
            for (int k2 = 0; k2 < 17; k2++) {
                int g1 = k1S + 8*k2;
                float4 av = Ag[(size_t)g1*HC];
                float2 xv = Xk[k2];
                z4[g1*RSC4 + g2n] = make_float4(
                    av.x*xv.x - av.y*xv.y, av.x*xv.y + av.y*xv.x,
                    av.z*xv.x - av.w*xv.y, av.z*xv.y + av.w*xv.x);
            }
        }
        __syncthreads();
        // Columns stage 1: 69*17 = 1173 items, both planes per item.
        for (int e = tid; e < HC*17; e += NTH) {
            int cc = (e*241) >> 12;
            int n2 = e - cc*17;
            fft136q_s1_body<1>(z4, tI136, cc, n2);
        }
        __syncthreads();
        // Columns stage 2: 552 items (rows -> slot136).
        if (tid < HC*8) {
            int cc = tid >> 3, k1 = tid & 7;
            dft17q<1>(z4, 17*k1*RSC4 + cc, RSC4);
        }
        __syncthreads();
        // Fused c2r pack + ct68 stage 1 (rows): 136*9 = 1224 items.
        for (int it = tid; it < MDIM*9; it += NTH) {
            int row = (it*7282) >> 16;                // it/9, it <= 1223
            int g   = it - row*9;
            int base = row*RSC4;
            if (g == 0) {
                float4 T0  = z4[base],    T17 = z4[base+17], T34 = z4[base+34],
                       T51 = z4[base+51], T68 = z4[base+68];
                float4 Z0 = c2r_pack4(T0,  T68, lutI[0]);
                float4 Z1 = c2r_pack4(T17, T51, lutI[17]);
                float4 Z2 = c2r_pack4(T34, T34, lutI[34]);
                float4 Z3 = c2r_pack4(T51, T17, lutI[51]);
                radix4q_tw<1>(z4, tI68, base, 0, Z0, Z1, Z2, Z3);
            } else {
                int gb = 17 - g;
                float4 Ta0 = z4[base+g],    Ta1 = z4[base+g+17],
                       Ta2 = z4[base+g+34], Ta3 = z4[base+g+51];
                float4 Tb0 = z4[base+gb],    Tb1 = z4[base+gb+17],
                       Tb2 = z4[base+gb+34], Tb3 = z4[base+gb+51];
                // partner of (g+17*n1) is (gb+17*(3-n1)), and vice versa
                float4 Za0 = c2r_pack4(Ta0, Tb3, lutI[g]);
                float4 Za1 = c2r_pack4(Ta1, Tb2, lutI[g+17]);
                float4 Za2 = c2r_pack4(Ta2, Tb1, lutI[g+34]);
                float4 Za3 = c2r_pack4(Ta3, Tb0, lutI[g+51]);
                float4 Zb0 = c2r_pack4(Tb0, Ta3, lutI[gb]);
                float4 Zb1 = c2r_pack4(Tb1, Ta2, lutI[gb+17]);
                float4 Zb2 = c2r_pack4(Tb2, Ta1, lutI[gb+34]);
                float4 Zb3 = c2r_pack4(Tb3, Ta0, lutI[gb+51]);
                radix4q_tw<1>(z4, tI68, base, g,  Za0, Za1, Za2, Za3);
                radix4q_tw<1>(z4, tI68, base, gb, Zb0, Zb1, Zb2, Zb3);
            }
        }
        __syncthreads();
        // ct68 stage 2 in place: 544 items.
        if (tid < MDIM*4) {
            int row = tid >> 2, k1 = tid & 3;
            dft17q<1>(z4, row*RSC4 + 17*k1, 1);
        }
        __syncthreads();
        // Dense float4 store: one b128 read = the output quad
        // (re_v0, re_v1, im_v0, im_v1) at cols [4m-8..4m-5].
        {
            int m  = 2 + (tid & 63);          // [2,66)
            int y1 = 4 + (tid >> 6);          // [4,20); +16/iter -> [4,132)
            int a  = slot136(y1)*RSC4 + slot68(m);
            float* rowp = op + (size_t)(2*y1 + u - 8)*256 + 4*m - 8;
#pragma unroll
            for (int it = 0; it < 8; ++it) {
                float4 w = z4[a];
                *reinterpret_cast<float4*>(rowp) = make_float4(w.x, w.z, w.y, w.w);
                a += 2*RSC4;                  // slot136(y1+16) = slot136(y1) + 2
                rowp += 32*256;
            }
        }
        __syncthreads();                      // z4 reads done before next u writes
    }
}

// ---------- Per-channel multiplier precompute (f32, R table in LDS) ----------
// Output: Abuf[(c*2+u)*PLANE_HALF + e] = (M_{u,v=0}.re, .im, M_{u,v=1}.re, .im)
__global__ void prep_kernel(const float* __restrict__ weight,
                            const float* __restrict__ bias,
                            float4* __restrict__ Abuf)
{
    __shared__ float tabc[272], tabs[272];    // exp(-2*pi*i*t/272)
    __shared__ float Rs[69*5*4];              // (g2*5+a)*4 + {R0r,R0i,R1r,R1i}
    for (int t = threadIdx.x; t < 272; t += blockDim.x) {
        float s, c; sincosf(-2.0f*(float)PI_D*(float)t/272.0f, &s, &c);
        tabc[t] = c; tabs[t] = s;
    }
    const int c     = blockIdx.x >> 3;
    const int chunk = blockIdx.x & 7;
    const float* wp = weight + c*25;
    const float r = 1.0f/(1.0f + expf(9.0f - bias[c])) + 1e-5f;
    __syncthreads();
    // R precompute: R{0,1}[a][g2] = sum_b w[a][b] (+/-)^b e2[b](g2). 345 items.
    for (int it = threadIdx.x; it < 69*5; it += blockDim.x) {
        int g2 = it / 5, a = it - 5*g2;
        float c2 = tabc[g2], s2 = tabs[g2];
        float e2r[5], e2i[5];
        e2r[2]=1.0f; e2i[2]=0.0f; e2r[3]=c2; e2i[3]=s2;
        e2r[4]=c2*c2-s2*s2; e2i[4]=2.0f*c2*s2;
        e2r[1]=c2; e2i[1]=-s2; e2r[0]=e2r[4]; e2i[0]=-e2i[4];
        float w0=wp[a*5+0], w1=wp[a*5+1], w2=wp[a*5+2], w3=wp[a*5+3], w4=wp[a*5+4];
        float Rer = w0*e2r[0] + w2*e2r[2] + w4*e2r[4];
        float Rei = w0*e2i[0] + w2*e2i[2] + w4*e2i[4];
        float Ror = w1*e2r[1] + w3*e2r[3];
        float Roi = w1*e2i[1] + w3*e2i[3];
        Rs[it*4+0] = Rer + Ror;  Rs[it*4+1] = Rei + Roi;   // R0
        Rs[it*4+2] = Rer - Ror;  Rs[it*4+3] = Rei - Roi;   // R1
    }
    __syncthreads();

    const int e_lo = chunk * 1173;           // 8*1173 == PLANE_HALF
    const int e_hi = e_lo + 1173;
    int e  = e_lo + (int)threadIdx.x;
    int g1 = e / HC, g2 = e - (e/HC)*HC;
    for (; e < e_hi; e += blockDim.x) {
        float c1 = tabc[g1], s1 = tabs[g1];
        float e1r[5], e1i[5];
        e1r[2]=1.0f; e1i[2]=0.0f; e1r[3]=c1; e1i[3]=s1;
        e1r[4]=c1*c1-s1*s1; e1i[4]=2.0f*c1*s1;
        e1r[1]=c1; e1i[1]=-s1; e1r[0]=e1r[4]; e1i[0]=-e1i[4];

        // FB[a1][b1] = sum_a (+/-)^(a*a1) e1[a] * R[b1][a], via even/odd-a split.
        float FBr[2][2], FBi[2][2];
#pragma unroll
        for (int b1 = 0; b1 < 2; b1++) {
            float Per=0.f, Pei=0.f, Por=0.f, Poi=0.f;
#pragma unroll
            for (int a = 0; a < 5; a++) {
                float Rr = Rs[(g2*5+a)*4 + 2*b1];
                float Ri = Rs[(g2*5+a)*4 + 2*b1 + 1];
                float tr = e1r[a]*Rr - e1i[a]*Ri;
                float ti = e1r[a]*Ri + e1i[a]*Rr;
                if (a & 1) { Por += tr; Poi += ti; } else { Per += tr; Pei += ti; }
            }
            FBr[0][b1] = Per + Por;  FBi[0][b1] = Pei + Poi;
            FBr[1][b1] = Per - Por;  FBi[1][b1] = Pei - Poi;
        }
        float c2 = tabc[g2], s2 = tabs[g2];
        float ur[2]={1.0f+c1, 1.0f-c1}, ui[2]={s1, -s1};
        float vr[2]={1.0f+c2, 1.0f-c2}, vi[2]={s2, -s2};
        float Br_[2][2], Bi_[2][2];
#pragma unroll
        for (int a1 = 0; a1 < 2; a1++)
#pragma unroll
            for (int b1 = 0; b1 < 2; b1++) {
                Br_[a1][b1] = ur[a1]*vr[b1] - ui[a1]*vi[b1];
                Bi_[a1][b1] = ur[a1]*vi[b1] + ui[a1]*vr[b1];
            }
        float invW=0.f, Qr=0.f, Qi=0.f;
#pragma unroll
        for (int a1 = 0; a1 < 2; a1++)
#pragma unroll
            for (int b1 = 0; b1 < 2; b1++) {
                invW += FBr[a1][b1]*FBr[a1][b1] + FBi[a1][b1]*FBi[a1][b1];
                Qr += FBr[a1][b1]*Br_[a1][b1] - FBi[a1][b1]*Bi_[a1][b1];
                Qi += FBr[a1][b1]*Bi_[a1][b1] + FBi[a1][b1]*Br_[a1][b1];
            }
        invW *= 0.25f; Qr *= 0.25f; Qi *= 0.25f;
        float den = 1.0f/(invW + r);
        float Sr = (1.0f - Qr)*den, Si = -Qi*den;
        float Mr[2][2], Mi[2][2];
#pragma unroll
        for (int a1 = 0; a1 < 2; a1++)
#pragma unroll
            for (int b1 = 0; b1 < 2; b1++) {
                Mr[a1][b1] = Br_[a1][b1] + FBr[a1][b1]*Sr + FBi[a1][b1]*Si;
                Mi[a1][b1] = Bi_[a1][b1] + FBr[a1][b1]*Si - FBi[a1][b1]*Sr;
            }
        const float scale = 1.0f/73984.0f;   // 1/272^2 ifft normalization
#pragma unroll
        for (int uu = 0; uu < 2; uu++) {
            float ov[4];
#pragma unroll
            for (int vv = 0; vv < 2; vv++) {
                float sr=0.f, si=0.f;
#pragma unroll
                for (int a1 = 0; a1 < 2; a1++)
#pragma unroll
                    for (int b1 = 0; b1 < 2; b1++) {
                        if ((a1*uu + b1*vv) & 1) { sr -= Mr[a1][b1]; si -= Mi[a1][b1]; }
                        else                     { sr += Mr[a1][b1]; si += Mi[a1][b1]; }
                    }
                int t = g1*uu + g2*vv;                 // <= 203 < 272
                float pc = tabc[t], ps = -tabs[t];     // exp(+i*pi*t/136)
                ov[2*vv]   = (pc*sr - ps*si)*scale;
                ov[2*vv+1] = (pc*si + ps*sr)*scale;
            }
            Abuf[((size_t)(c*2 + uu))*PLANE_HALF + e] =
                make_float4(ov[0], ov[1], ov[2], ov[3]);
        }
        g1 += 3; g2 += 49; if (g2 >= HC) { g2 -= HC; g1++; }   // e += 256
    }
}

extern "C" void kernel_launch(void* const* d_in, const int* in_sizes, int n_in,
                              void* d_out, int out_size, void* d_ws, size_t ws_size,
                              hipStream_t stream)
{
    const float* x      = (const float*)d_in[0];
    const float* weight = (const float*)d_in[1];
    const float* bias   = (const float*)d_in[2];
    float* out = (float*)d_out;

    float4* Abuf = (float4*)d_ws;     // 128 * 9384 * 16B = 19.2 MB

    (void)hipFuncSetAttribute((const void*)conv_kernel,
                              hipFuncAttributeMaxDynamicSharedMemorySize,
                              (int)LDS_BYTES);

    prep_kernel<<<512, 256, 0, stream>>>(weight, bias, Abuf);
    conv_kernel<<<NPLANES, 1024, LDS_BYTES, stream>>>(x, Abuf, out);
}

// Round 11
// 142.290 us; speedup vs baseline: 1.2996x; 1.2996x over previous
//
#include <hip/hip_runtime.h>
#include <math.h>

// Converse2D on gfx950 — spectral restructuring (R13, resubmit — prior bench
// failed on container infrastructure, no counters produced):
//   out(2y+u, 2x+v) plane = ifft136( A_uv[g] * Xhat[g] ), per (n,c,u,v)
//   Xhat = rfft136x136(wrap_pad(x)); A_uv = per-channel multiplier (Hermitian).
// R13 = R12 piece 1 only (A/B isolation):
//   KEPT: RSC4=73 (row stride 292 dwords == 4 mod 32; conflicts 6.27M->4.15M
//         measured in R12), inverse-only twiddle tables conjugated at use.
//   REVERTED: Xk[17] register fusion (R12's spill: VGPR pinned 64, 34-reg
//         array -> scratch, WRITE 85->252MB, conv 67->114us). Back to R11's
//         in-place cols-s2 -> Xreg[10] capture -> S-phase with direct A-loads.

#define MDIM 136
#define RSCF 146            // fwd float2 view: row stride (float2 units) = 2*RSC4
#define RSC4 73             // inverse float4 view: row stride (float4 units)
#define HC   69             // stored Hermitian half columns (0..68)
#define PLANE_HALF (MDIM*HC)   // 9384 per plane
#define NPLANES 256         // N*C
#define LDS_BYTES (MDIM*RSC4*16 + 306*8)   // plane + lutI/tI136/tI68 = 161,296 B
#define PI_D 3.14159265358979323846
#define NTH 1024

__device__ __forceinline__ int slot136(int k) { return 17*(k & 7) + (k >> 3); }
__device__ __forceinline__ int slot68(int k)  { return 17*(k & 3) + (k >> 2); }

// ---------- float4 "dual-complex" helpers: q = (re0, im0, re1, im1) ----------
__device__ __forceinline__ float4 q_add(float4 a, float4 b)
{ return make_float4(a.x+b.x, a.y+b.y, a.z+b.z, a.w+b.w); }
__device__ __forceinline__ float4 q_sub(float4 a, float4 b)
{ return make_float4(a.x-b.x, a.y-b.y, a.z-b.z, a.w-b.w); }
__device__ __forceinline__ float4 q_muli(float4 a, float d)   // d * (i*a), both halves
{ return make_float4(-d*a.y, d*a.x, -d*a.w, d*a.z); }
__device__ __forceinline__ float4 q_scale(float4 a, float s)
{ return make_float4(s*a.x, s*a.y, s*a.z, s*a.w); }
__device__ __forceinline__ float4 q_fma(float4 a, float s, float4 acc)
{ return make_float4(fmaf(a.x,s,acc.x), fmaf(a.y,s,acc.y),
                     fmaf(a.z,s,acc.z), fmaf(a.w,s,acc.w)); }
__device__ __forceinline__ float4 cmul4(float4 q, float2 w)   // same twiddle, both halves
{ return make_float4(q.x*w.x - q.y*w.y, q.x*w.y + q.y*w.x,
                     q.z*w.x - q.w*w.y, q.z*w.y + q.w*w.x); }

// ---------- symmetric 17-point DFT (float2, fwd), strided, sink outputs ----------
template<int DIR, class F>
__device__ __forceinline__ void dft17_sink(float2* z, int base, int stride, F f)
{
    constexpr float C17[9] = {1.f, 0.93247223f, 0.73900892f, 0.44573836f,
                              0.09226836f, -0.27366299f, -0.60263464f,
                              -0.85021714f, -0.98297310f};
    constexpr float S17[9] = {0.f, 0.36124167f, 0.67369564f, 0.89516329f,
                              0.99573418f, 0.96182564f, 0.79801723f,
                              0.52643216f, 0.18374952f};
    constexpr float d = (DIR > 0) ? 1.f : -1.f;
    float xr[17], xi[17];
#pragma unroll
    for (int n = 0; n < 17; n++) {
        float2 v = z[base + n*stride];
        xr[n] = v.x; xi[n] = v.y;
    }
    float ar[8], ai[8], br[8], bi[8];
#pragma unroll
    for (int n = 1; n <= 8; n++) {
        ar[n-1] = xr[n] + xr[17-n];  ai[n-1] = xi[n] + xi[17-n];
        br[n-1] = xr[n] - xr[17-n];  bi[n-1] = xi[n] - xi[17-n];
    }
    float s0r = xr[0], s0i = xi[0];
#pragma unroll
    for (int n = 0; n < 8; n++) { s0r += ar[n]; s0i += ai[n]; }
    f(0, s0r, s0i);
#pragma unroll
    for (int k = 1; k <= 8; k++) {
        float Pr = xr[0], Pi = xi[0], Qr = 0.f, Qi = 0.f;
#pragma unroll
        for (int n = 1; n <= 8; n++) {
            int m = (k*n) % 17;
            float cc = (m <= 8) ? C17[m] : C17[17-m];
            float ss = (m <= 8) ? S17[m] : -S17[17-m];
            Pr = fmaf(ar[n-1], cc, Pr);
            Pi = fmaf(ai[n-1], cc, Pi);
            Qr = fmaf(br[n-1], ss, Qr);
            Qi = fmaf(bi[n-1], ss, Qi);
        }
        f(k,    Pr - d*Qi, Pi + d*Qr);
        f(17-k, Pr + d*Qi, Pi - d*Qr);
    }
}

// ---------- symmetric 17-point DFT (float4 dual-plane), strided, in-place ----------
template<int DIR>
__device__ __forceinline__ void dft17q(float4* z, int base, int stride)
{
    constexpr float C17[9] = {1.f, 0.93247223f, 0.73900892f, 0.44573836f,
                              0.09226836f, -0.27366299f, -0.60263464f,
                              -0.85021714f, -0.98297310f};
    constexpr float S17[9] = {0.f, 0.36124167f, 0.67369564f, 0.89516329f,
                              0.99573418f, 0.96182564f, 0.79801723f,
                              0.52643216f, 0.18374952f};
    constexpr float d = (DIR > 0) ? 1.f : -1.f;
    float4 x0 = z[base];
    float4 a[8], b[8];
#pragma unroll
    for (int n = 1; n <= 8; n++) {
        float4 u = z[base + n*stride];
        float4 v = z[base + (17-n)*stride];
        a[n-1] = q_add(u, v);
        b[n-1] = q_sub(u, v);
    }
    float4 s0 = x0;
#pragma unroll
    for (int n = 0; n < 8; n++) s0 = q_add(s0, a[n]);
    z[base] = s0;
#pragma unroll
    for (int k = 1; k <= 8; k++) {
        float4 P = x0, Q = make_float4(0.f,0.f,0.f,0.f);
#pragma unroll
        for (int n = 1; n <= 8; n++) {
            int m = (k*n) % 17;
            float cc = (m <= 8) ? C17[m] : C17[17-m];
            float ss = (m <= 8) ? S17[m] : -S17[17-m];
            P = q_fma(a[n-1], cc, P);
            Q = q_fma(b[n-1], ss, Q);
        }
        float4 iq = q_muli(Q, d);
        z[base + k*stride]      = q_add(P, iq);
        z[base + (17-k)*stride] = q_sub(P, iq);
    }
}

// ---------- radix-4 + table twiddle (float2; tables are INVERSE-dir, DIR<0 conj) ----------
template<int DIR>
__device__ __forceinline__ void radix4_tw(float2* z, const float2* t68, int base, int n2,
                                          float2 Z0, float2 Z1, float2 Z2, float2 Z3)
{
    constexpr float d = (DIR > 0) ? 1.0f : -1.0f;
    float t0r = Z0.x+Z2.x, t0i = Z0.y+Z2.y;
    float t1r = Z0.x-Z2.x, t1i = Z0.y-Z2.y;
    float t2r = Z1.x+Z3.x, t2i = Z1.y+Z3.y;
    float t3r = Z1.x-Z3.x, t3i = Z1.y-Z3.y;
    float X0r = t0r+t2r,     X0i = t0i+t2i;
    float X2r = t0r-t2r,     X2i = t0i-t2i;
    float X1r = t1r - d*t3i, X1i = t1i + d*t3r;
    float X3r = t1r + d*t3i, X3i = t1i - d*t3r;
    z[base + n2] = make_float2(X0r, X0i);
    float2 w1 = t68[n2], w2 = t68[17 + n2], w3 = t68[34 + n2];
    if (DIR < 0) { w1.y = -w1.y; w2.y = -w2.y; w3.y = -w3.y; }
    z[base + 17 + n2] = make_float2(X1r*w1.x - X1i*w1.y, X1r*w1.y + X1i*w1.x);
    z[base + 34 + n2] = make_float2(X2r*w2.x - X2i*w2.y, X2r*w2.y + X2i*w2.x);
    z[base + 51 + n2] = make_float2(X3r*w3.x - X3i*w3.y, X3r*w3.y + X3i*w3.x);
}

// ---------- radix-4 + table twiddle (float4 dual-plane, inverse only) ----------
template<int DIR>
__device__ __forceinline__ void radix4q_tw(float4* z, const float2* t68, int base, int n2,
                                           float4 Z0, float4 Z1, float4 Z2, float4 Z3)
{
    constexpr float d = (DIR > 0) ? 1.0f : -1.0f;
    float4 t0 = q_add(Z0, Z2), t1 = q_sub(Z0, Z2);
    float4 t2 = q_add(Z1, Z3), t3 = q_sub(Z1, Z3);
    float4 X0 = q_add(t0, t2), X2 = q_sub(t0, t2);
    float4 it3 = q_muli(t3, d);
    float4 X1 = q_add(t1, it3), X3 = q_sub(t1, it3);
    z[base + n2] = X0;
    float2 w1 = t68[n2], w2 = t68[17 + n2], w3 = t68[34 + n2];
    z[base + 17 + n2] = cmul4(X1, w1);
    z[base + 34 + n2] = cmul4(X2, w2);
    z[base + 51 + n2] = cmul4(X3, w3);
}

// ---------- 136-pt CT stage 1 (radix-8 + table twiddle), float2 fwd ----------
template<int DIR>
__device__ __forceinline__ void fft136_s1_body(float2* z, const float2* t136,
                                               int c, int n2)
{
    constexpr float d = (DIR > 0) ? 1.0f : -1.0f;
    constexpr float C707 = 0.70710678118654752f;
    float xr[8], xi[8];
#pragma unroll
    for (int n1 = 0; n1 < 8; n1++) {
        float2 v = z[(17*n1 + n2)*RSCF + c];
        xr[n1] = v.x; xi[n1] = v.y;
    }
    float e0r = xr[0]+xr[4], e0i = xi[0]+xi[4];
    float e1r = xr[0]-xr[4], e1i = xi[0]-xi[4];
    float o0r = xr[2]+xr[6], o0i = xi[2]+xi[6];
    float o1r = xr[2]-xr[6], o1i = xi[2]-xi[6];
    float E0r = e0r+o0r, E0i = e0i+o0i;
    float E2r = e0r-o0r, E2i = e0i-o0i;
    float E1r = e1r - d*o1i, E1i = e1i + d*o1r;
    float E3r = e1r + d*o1i, E3i = e1i - d*o1r;
    float f0r = xr[1]+xr[5], f0i = xi[1]+xi[5];
    float f1r = xr[1]-xr[5], f1i = xi[1]-xi[5];
    float h0r = xr[3]+xr[7], h0i = xi[3]+xi[7];
    float h1r = xr[3]-xr[7], h1i = xi[3]-xi[7];
    float O0r = f0r+h0r, O0i = f0i+h0i;
    float O2r = f0r-h0r, O2i = f0i-h0i;
    float O1r = f1r - d*h1i, O1i = f1i + d*h1r;
    float O3r = f1r + d*h1i, O3i = f1i - d*h1r;
    float t1r =  C707*(O1r - d*O1i), t1i = C707*(O1i + d*O1r);
    float t2r = -d*O2i,              t2i = d*O2r;
    float t3r = -C707*(O3r + d*O3i), t3i = C707*(d*O3r - O3i);
    float Xr[8], Xi[8];
    Xr[0]=E0r+O0r; Xi[0]=E0i+O0i;  Xr[4]=E0r-O0r; Xi[4]=E0i-O0i;
    Xr[1]=E1r+t1r; Xi[1]=E1i+t1i;  Xr[5]=E1r-t1r; Xi[5]=E1i-t1i;
    Xr[2]=E2r+t2r; Xi[2]=E2i+t2i;  Xr[6]=E2r-t2r; Xi[6]=E2i-t2i;
    Xr[3]=E3r+t3r; Xi[3]=E3i+t3i;  Xr[7]=E3r-t3r; Xi[7]=E3i-t3i;
    z[n2*RSCF + c] = make_float2(Xr[0], Xi[0]);
#pragma unroll
    for (int k1 = 1; k1 < 8; k1++) {
        float2 w = t136[(k1-1)*17 + n2];
        if (DIR < 0) w.y = -w.y;
        z[(17*k1 + n2)*RSCF + c] = make_float2(Xr[k1]*w.x - Xi[k1]*w.y,
                                               Xr[k1]*w.y + Xi[k1]*w.x);
    }
}

// ---------- 136-pt CT stage 1 (radix-8 + table twiddle), float4 dual-plane ----------
template<int DIR>
__device__ __forceinline__ void fft136q_s1_body(float4* z, const float2* t136,
                                                int c, int n2)
{
    constexpr float d = (DIR > 0) ? 1.0f : -1.0f;
    constexpr float C707 = 0.70710678118654752f;
    float4 x[8];
#pragma unroll
    for (int n1 = 0; n1 < 8; n1++) x[n1] = z[(17*n1 + n2)*RSC4 + c];
    float4 e0 = q_add(x[0], x[4]), e1 = q_sub(x[0], x[4]);
    float4 o0 = q_add(x[2], x[6]), o1 = q_sub(x[2], x[6]);
    float4 E0 = q_add(e0, o0), E2 = q_sub(e0, o0);
    float4 io1 = q_muli(o1, d);
    float4 E1 = q_add(e1, io1), E3 = q_sub(e1, io1);
    float4 f0 = q_add(x[1], x[5]), f1 = q_sub(x[1], x[5]);
    float4 h0 = q_add(x[3], x[7]), h1 = q_sub(x[3], x[7]);
    float4 O0 = q_add(f0, h0), O2 = q_sub(f0, h0);
    float4 ih1 = q_muli(h1, d);
    float4 O1 = q_add(f1, ih1), O3 = q_sub(f1, ih1);
    float4 t1 = q_scale(q_add(O1, q_muli(O1, d)), C707);
    float4 t2 = q_muli(O2, d);
    float4 t3 = q_scale(q_sub(O3, q_muli(O3, d)), -C707);
    float4 X0 = q_add(E0, O0), X4 = q_sub(E0, O0);
    float4 X1 = q_add(E1, t1), X5 = q_sub(E1, t1);
    float4 X2 = q_add(E2, t2), X6 = q_sub(E2, t2);
    float4 X3 = q_add(E3, t3), X7 = q_sub(E3, t3);
    z[n2*RSC4 + c] = X0;
    z[(17*1 + n2)*RSC4 + c] = cmul4(X1, t136[0*17 + n2]);
    z[(17*2 + n2)*RSC4 + c] = cmul4(X2, t136[1*17 + n2]);
    z[(17*3 + n2)*RSC4 + c] = cmul4(X3, t136[2*17 + n2]);
    z[(17*4 + n2)*RSC4 + c] = cmul4(X4, t136[3*17 + n2]);
    z[(17*5 + n2)*RSC4 + c] = cmul4(X5, t136[4*17 + n2]);
    z[(17*6 + n2)*RSC4 + c] = cmul4(X6, t136[5*17 + n2]);
    z[(17*7 + n2)*RSC4 + c] = cmul4(X7, t136[6*17 + n2]);
}

// c2r pack (float4 dual-plane), same w both halves.
__device__ __forceinline__ float4 c2r_pack4(float4 a, float4 b, float2 w)
{
    float Sx = a.x + b.x, Sy = a.y - b.y;
    float Dx = a.x - b.x, Dy = a.y + b.y;
    float Ox = w.x*Dx - w.y*Dy, Oy = w.x*Dy + w.y*Dx;
    float Sz = a.z + b.z, Sw = a.w - b.w;
    float Dz = a.z - b.z, Dw = a.w + b.w;
    float Oz = w.x*Dz - w.y*Dw, Ow = w.x*Dw + w.y*Dz;
    return make_float4(Sx - Oy, Sy + Ox, Sz - Ow, Sw + Oz);
}

// ---------- Fused forward + inverse: one WG per (n,c) plane (256 WGs) ----------
__global__ __launch_bounds__(1024, 4) void conv_kernel(const float* __restrict__ x,
                                                       const float4* __restrict__ Abuf,
                                                       float* __restrict__ out)
{
    extern __shared__ float4 z4s[];
    float4* z4    = z4s;                      // inverse: [136][73] dual-plane
    float2* zf    = (float2*)z4s;             // fwd view: row stride 146, cols 0..68
    float2* lutI  = (float2*)(z4s + MDIM*RSC4);   // exp(+2*pi*i*t/136)
    float2* tI136 = lutI + MDIM;              // [7][17]: w136^(k1*n2), inverse dir
    float2* tI68  = tI136 + 119;              // [3][17]: w68^((j+1)*n2), inverse dir
    const int tid = threadIdx.x;
    const int nc  = blockIdx.x;               // n*64 + c
    const int c   = nc & 63;

    if (tid < MDIM) {
        float s, cc; sincosf(2.0f*(float)PI_D*(float)tid/136.0f, &s, &cc);
        lutI[tid] = make_float2(cc, s);
    } else if (tid < MDIM + 119) {
        int it = tid - MDIM;
        int k1 = it/17 + 1, n2 = it - (it/17)*17;
        float s, cc; sincosf((float)(PI_D/68.0)*(float)(k1*n2), &s, &cc);
        tI136[it] = make_float2(cc, s);
    } else if (tid < MDIM + 119 + 51) {
        int it = tid - MDIM - 119;
        int j = it/17, n2 = it - 17*j;
        float s, cc; sincosf((float)(PI_D/34.0)*(float)((j+1)*n2), &s, &cc);
        tI68[it] = make_float2(cc, s);
    }
    // ---------------- forward on zf (stride RSCF) ----------------
    const float* xp = x + (size_t)nc * (128*128);
    {   // packed-row load: zf[i][n] = xp(i,2n) + i*xp(i,2n+1), wrap pad by 4
        int i = tid / 68, n = tid - (tid/68)*68;
        for (int e = tid; e < MDIM*68; e += NTH) {
            int si = (i + 124) & 127;
            int j0 = (2*n + 124) & 127;              // always even, pair never wraps
            zf[i*RSCF + n] = *reinterpret_cast<const float2*>(xp + si*128 + j0);
            i += 15; n += 4; if (n >= 68) { n -= 68; i++; }
        }
    }
    __syncthreads();
    {   // rows stage 1 (radix-4)
        int row = tid / 17;
        int n2  = tid - row*17;
        for (int e = tid; e < MDIM*17; e += NTH) {
            int base = row*RSCF;
            float2 Z0 = zf[base + n2];
            float2 Z1 = zf[base + 17 + n2];
            float2 Z2 = zf[base + 34 + n2];
            float2 Z3 = zf[base + 51 + n2];
            radix4_tw<-1>(zf, tI68, base, n2, Z0, Z1, Z2, Z3);
            row += 60; n2 += 4; if (n2 >= 17) { n2 -= 17; row++; }
        }
    }
    __syncthreads();
    if (tid < MDIM*4) {                              // rows stage 2: Z[k] at slot68(k)
        int row = tid >> 2, k1 = tid & 3;
        int base = row*RSCF + 17*k1;
        dft17_sink<-1>(zf, base, 1, [&](int k2, float re, float im) {
            zf[base + k2] = make_float2(re, im);
        });
    }
    __syncthreads();
    {   // r2c unpack: item k handles (k, 68-k), in-place at slots
        int row = tid / 35, k = tid - (tid/35)*35;
        for (int e = tid; e < MDIM*35; e += NTH) {
            int base = row*RSCF;
            int sa = slot68(k);
            float2 Za = zf[base+sa];
            float Zar = Za.x, Zai = Za.y;
            float Zbr, Zbi; int sb;
            if (k == 0) { Zbr = Zar; Zbi = Zai; sb = 68; }  // Z[68]==Z[0]; X[68]->col 68
            else {
                int kk = 68-k; sb = slot68(kk);
                float2 Zb = zf[base+sb]; Zbr = Zb.x; Zbi = Zb.y;
            }
            float2 w = lutI[k];                             // conj -> fwd w136^k
            float wc = w.x, ws = -w.y;
            float Er = 0.5f*(Zar + Zbr), Ei = 0.5f*(Zai - Zbi);
            float Dr = 0.5f*(Zar - Zbr), Di = 0.5f*(Zai + Zbi);
            float Tr = wc*Dr - ws*Di, Ti = wc*Di + ws*Dr;   // w^k * D
            zf[base+sa] = make_float2(Er + Ti, Ei - Tr);    // X[k] = E - i*(w^k D)
            float E2r = Er,  E2i = -Ei;
            float D2r = -Dr, D2i = Di;
            float w2c = -wc, w2s = ws;                      // w136^(68-k) = -conj(w^k)
            float T2r = w2c*D2r - w2s*D2i, T2i = w2c*D2i + w2s*D2r;
            zf[base+sb] = make_float2(E2r + T2i, E2i - T2r); // X[68-k]
            row += 29; k += 9; if (k >= 35) { k -= 35; row++; }
        }
    }
    __syncthreads();
    for (int e = tid; e < HC*17; e += NTH) {         // columns stage 1 (69 cols)
        int cc = (e*241) >> 12;                      // e/17, e <= 1172
        int n2 = e - cc*17;
        fft136_s1_body<-1>(zf, tI136, cc, n2);
    }
    __syncthreads();
    if (tid < HC*8) {                                // columns stage 2, in place
        int cc = tid >> 3, k1 = tid & 7;
        int base = 17*k1*RSCF + cc;
        dft17_sink<-1>(zf, base, RSCF, [&](int k2, float re, float im) {
            zf[base + k2*RSCF] = make_float2(re, im);
        });
    }
    __syncthreads();
    // ---------------- capture Xhat to registers ----------------
    float2 Xreg[10];
    {
        int g1 = tid / HC, g2 = tid - (tid/HC)*HC;
#pragma unroll
        for (int k = 0; k < 10; k++) {
            if (k < 9 || tid < PLANE_HALF - 9*NTH) {     // tail: 168 threads
                int cq = (g2 == 68) ? 68 : slot68(g2);
                Xreg[k] = zf[slot136(g1)*RSCF + cq];
            }
            g1 += 14; g2 += 58; if (g2 >= HC) { g2 -= HC; g1++; }
        }
    }
    __syncthreads();
    // ---------------- inverse, u = 0,1; both v-planes in z4 ----------------
    float* op = out + (size_t)nc * (256*256);
#pragma unroll 1
    for (int u = 0; u < 2; u++) {
        const float4* Ap = Abuf + (size_t)(c*2 + u) * PLANE_HALF;
        {   // S = A_uv * Xhat (both v), natural [g1][g2]; one 16B A-load/elem
            int g1 = tid / HC, g2 = tid - (tid/HC)*HC;
#pragma unroll
            for (int k = 0; k < 10; k++) {
                if (k < 9 || tid < PLANE_HALF - 9*NTH) {
                    float2 xv = Xreg[k];
                    float4 av = Ap[tid + k*NTH];
                    z4[g1*RSC4 + g2] = make_float4(
                        av.x*xv.x - av.y*xv.y, av.x*xv.y + av.y*xv.x,
                        av.z*xv.x - av.w*xv.y, av.z*xv.y + av.w*xv.x);
                }
                g1 += 14; g2 += 58; if (g2 >= HC) { g2 -= HC; g1++; }
            }
        }
        __syncthreads();
        // Columns stage 1: 69*17 = 1173 items, both planes per item.
        for (int e = tid; e < HC*17; e += NTH) {
            int cc = (e*241) >> 12;
            int n2 = e - cc*17;
            fft136q_s1_body<1>(z4, tI136, cc, n2);
        }
        __syncthreads();
        // Columns stage 2: 552 items (rows -> slot136).
        if (tid < HC*8) {
            int cc = tid >> 3, k1 = tid & 7;
            dft17q<1>(z4, 17*k1*RSC4 + cc, RSC4);
        }
        __syncthreads();
        // Fused c2r pack + ct68 stage 1 (rows): 136*9 = 1224 items.
        for (int it = tid; it < MDIM*9; it += NTH) {
            int row = (it*7282) >> 16;                // it/9, it <= 1223
            int g   = it - row*9;
            int base = row*RSC4;
            if (g == 0) {
                float4 T0  = z4[base],    T17 = z4[base+17], T34 = z4[base+34],
                       T51 = z4[base+51], T68 = z4[base+68];
                float4 Z0 = c2r_pack4(T0,  T68, lutI[0]);
                float4 Z1 = c2r_pack4(T17, T51, lutI[17]);
                float4 Z2 = c2r_pack4(T34, T34, lutI[34]);
                float4 Z3 = c2r_pack4(T51, T17, lutI[51]);
                radix4q_tw<1>(z4, tI68, base, 0, Z0, Z1, Z2, Z3);
            } else {
                int gb = 17 - g;
                float4 Ta0 = z4[base+g],    Ta1 = z4[base+g+17],
                       Ta2 = z4[base+g+34], Ta3 = z4[base+g+51];
                float4 Tb0 = z4[base+gb],    Tb1 = z4[base+gb+17],
                       Tb2 = z4[base+gb+34], Tb3 = z4[base+gb+51];
                // partner of (g+17*n1) is (gb+17*(3-n1)), and vice versa
                float4 Za0 = c2r_pack4(Ta0, Tb3, lutI[g]);
                float4 Za1 = c2r_pack4(Ta1, Tb2, lutI[g+17]);
                float4 Za2 = c2r_pack4(Ta2, Tb1, lutI[g+34]);
                float4 Za3 = c2r_pack4(Ta3, Tb0, lutI[g+51]);
                float4 Zb0 = c2r_pack4(Tb0, Ta3, lutI[gb]);
                float4 Zb1 = c2r_pack4(Tb1, Ta2, lutI[gb+17]);
                float4 Zb2 = c2r_pack4(Tb2, Ta1, lutI[gb+34]);
                float4 Zb3 = c2r_pack4(Tb3, Ta0, lutI[gb+51]);
                radix4q_tw<1>(z4, tI68, base, g,  Za0, Za1, Za2, Za3);
                radix4q_tw<1>(z4, tI68, base, gb, Zb0, Zb1, Zb2, Zb3);
            }
        }
        __syncthreads();
        // ct68 stage 2 in place: 544 items.
        if (tid < MDIM*4) {
            int row = tid >> 2, k1 = tid & 3;
            dft17q<1>(z4, row*RSC4 + 17*k1, 1);
        }
        __syncthreads();
        // Dense float4 store: one b128 read = the output quad
        // (re_v0, re_v1, im_v0, im_v1) at cols [4m-8..4m-5].
        {
            int m  = 2 + (tid & 63);          // [2,66)
            int y1 = 4 + (tid >> 6);          // [4,20); +16/iter -> [4,132)
            int a  = slot136(y1)*RSC4 + slot68(m);
            float* rowp = op + (size_t)(2*y1 + u - 8)*256 + 4*m - 8;
#pragma unroll
            for (int it = 0; it < 8; ++it) {
                float4 w = z4[a];
                *reinterpret_cast<float4*>(rowp) = make_float4(w.x, w.z, w.y, w.w);
                a += 2*RSC4;                  // slot136(y1+16) = slot136(y1) + 2
                rowp += 32*256;
            }
        }
        __syncthreads();                      // z4 reads done before next u writes
    }
}

// ---------- Per-channel multiplier precompute (f32, R table in LDS) ----------
// Output: Abuf[(c*2+u)*PLANE_HALF + e] = (M_{u,v=0}.re, .im, M_{u,v=1}.re, .im)
__global__ void prep_kernel(const float* __restrict__ weight,
                            const float* __restrict__ bias,
                            float4* __restrict__ Abuf)
{
    __shared__ float tabc[272], tabs[272];    // exp(-2*pi*i*t/272)
    __shared__ float Rs[69*5*4];              // (g2*5+a)*4 + {R0r,R0i,R1r,R1i}
    for (int t = threadIdx.x; t < 272; t += blockDim.x) {
        float s, c; sincosf(-2.0f*(float)PI_D*(float)t/272.0f, &s, &c);
        tabc[t] = c; tabs[t] = s;
    }
    const int c     = blockIdx.x >> 3;
    const int chunk = blockIdx.x & 7;
    const float* wp = weight + c*25;
    const float r = 1.0f/(1.0f + expf(9.0f - bias[c])) + 1e-5f;
    __syncthreads();
    // R precompute: R{0,1}[a][g2] = sum_b w[a][b] (+/-)^b e2[b](g2). 345 items.
    for (int it = threadIdx.x; it < 69*5; it += blockDim.x) {
        int g2 = it / 5, a = it - 5*g2;
        float c2 = tabc[g2], s2 = tabs[g2];
        float e2r[5], e2i[5];
        e2r[2]=1.0f; e2i[2]=0.0f; e2r[3]=c2; e2i[3]=s2;
        e2r[4]=c2*c2-s2*s2; e2i[4]=2.0f*c2*s2;
        e2r[1]=c2; e2i[1]=-s2; e2r[0]=e2r[4]; e2i[0]=-e2i[4];
        float w0=wp[a*5+0], w1=wp[a*5+1], w2=wp[a*5+2], w3=wp[a*5+3], w4=wp[a*5+4];
        float Rer = w0*e2r[0] + w2*e2r[2] + w4*e2r[4];
        float Rei = w0*e2i[0] + w2*e2i[2] + w4*e2i[4];
        float Ror = w1*e2r[1] + w3*e2r[3];
        float Roi = w1*e2i[1] + w3*e2i[3];
        Rs[it*4+0] = Rer + Ror;  Rs[it*4+1] = Rei + Roi;   // R0
        Rs[it*4+2] = Rer - Ror;  Rs[it*4+3] = Rei - Roi;   // R1
    }
    __syncthreads();

    const int e_lo = chunk * 1173;           // 8*1173 == PLANE_HALF
    const int e_hi = e_lo + 1173;
    int e  = e_lo + (int)threadIdx.x;
    int g1 = e / HC, g2 = e - (e/HC)*HC;
    for (; e < e_hi; e += blockDim.x) {
        float c1 = tabc[g1], s1 = tabs[g1];
        float e1r[5], e1i[5];
        e1r[2]=1.0f; e1i[2]=0.0f; e1r[3]=c1; e1i[3]=s1;
        e1r[4]=c1*c1-s1*s1; e1i[4]=2.0f*c1*s1;
        e1r[1]=c1; e1i[1]=-s1; e1r[0]=e1r[4]; e1i[0]=-e1i[4];

        // FB[a1][b1] = sum_a (+/-)^(a*a1) e1[a] * R[b1][a], via even/odd-a split.
        float FBr[2][2], FBi[2][2];
#pragma unroll
        for (int b1 = 0; b1 < 2; b1++) {
            float Per=0.f, Pei=0.f, Por=0.f, Poi=0.f;
#pragma unroll
            for (int a = 0; a < 5; a++) {
                float Rr = Rs[(g2*5+a)*4 + 2*b1];
                float Ri = Rs[(g2*5+a)*4 + 2*b1 + 1];
                float tr = e1r[a]*Rr - e1i[a]*Ri;
                float ti = e1r[a]*Ri + e1i[a]*Rr;
                if (a & 1) { Por += tr; Poi += ti; } else { Per += tr; Pei += ti; }
            }
            FBr[0][b1] = Per + Por;  FBi[0][b1] = Pei + Poi;
            FBr[1][b1] = Per - Por;  FBi[1][b1] = Pei - Poi;
        }
        float c2 = tabc[g2], s2 = tabs[g2];
        float ur[2]={1.0f+c1, 1.0f-c1}, ui[2]={s1, -s1};
        float vr[2]={1.0f+c2, 1.0f-c2}, vi[2]={s2, -s2};
        float Br_[2][2], Bi_[2][2];
#pragma unroll
        for (int a1 = 0; a1 < 2; a1++)
#pragma unroll
            for (int b1 = 0; b1 < 2; b1++) {
                Br_[a1][b1] = ur[a1]*vr[b1] - ui[a1]*vi[b1];
                Bi_[a1][b1] = ur[a1]*vi[b1] + ui[a1]*vr[b1];
            }
        float invW=0.f, Qr=0.f, Qi=0.f;
#pragma unroll
        for (int a1 = 0; a1 < 2; a1++)
#pragma unroll
            for (int b1 = 0; b1 < 2; b1++) {
                invW += FBr[a1][b1]*FBr[a1][b1] + FBi[a1][b1]*FBi[a1][b1];
                Qr += FBr[a1][b1]*Br_[a1][b1] - FBi[a1][b1]*Bi_[a1][b1];
                Qi += FBr[a1][b1]*Bi_[a1][b1] + FBi[a1][b1]*Br_[a1][b1];
            }
        invW *= 0.25f; Qr *= 0.25f; Qi *= 0.25f;
        float den = 1.0f/(invW + r);
        float Sr = (1.0f - Qr)*den, Si = -Qi*den;
        float Mr[2][2], Mi[2][2];
#pragma unroll
        for (int a1 = 0; a1 < 2; a1++)
#pragma unroll
            for (int b1 = 0; b1 < 2; b1++) {
                Mr[a1][b1] = Br_[a1][b1] + FBr[a1][b1]*Sr + FBi[a1][b1]*Si;
                Mi[a1][b1] = Bi_[a1][b1] + FBr[a1][b1]*Si - FBi[a1][b1]*Sr;
            }
        const float scale = 1.0f/73984.0f;   // 1/272^2 ifft normalization
#pragma unroll
        for (int uu = 0; uu < 2; uu++) {
            float ov[4];
#pragma unroll
            for (int vv = 0; vv < 2; vv++) {
                float sr=0.f, si=0.f;
#pragma unroll
                for (int a1 = 0; a1 < 2; a1++)
#pragma unroll
                    for (int b1 = 0; b1 < 2; b1++) {
                        if ((a1*uu + b1*vv) & 1) { sr -= Mr[a1][b1]; si -= Mi[a1][b1]; }
                        else                     { sr += Mr[a1][b1]; si += Mi[a1][b1]; }
                    }
                int t = g1*uu + g2*vv;                 // <= 203 < 272
                float pc = tabc[t], ps = -tabs[t];     // exp(+i*pi*t/136)
                ov[2*vv]   = (pc*sr - ps*si)*scale;
                ov[2*vv+1] = (pc*si + ps*sr)*scale;
            }
            Abuf[((size_t)(c*2 + uu))*PLANE_HALF + e] =
                make_float4(ov[0], ov[1], ov[2], ov[3]);
        }
        g1 += 3; g2 += 49; if (g2 >= HC) { g2 -= HC; g1++; }   // e += 256
    }
}

extern "C" void kernel_launch(void* const* d_in, const int* in_sizes, int n_in,
                              void* d_out, int out_size, void* d_ws, size_t ws_size,
                              hipStream_t stream)
{
    const float* x      = (const float*)d_in[0];
    const float* weight = (const float*)d_in[1];
    const float* bias   = (const float*)d_in[2];
    float* out = (float*)d_out;

    float4* Abuf = (float4*)d_ws;     // 128 * 9384 * 16B = 19.2 MB

    (void)hipFuncSetAttribute((const void*)conv_kernel,
                              hipFuncAttributeMaxDynamicSharedMemorySize,
                              (int)LDS_BYTES);

    prep_kernel<<<512, 256, 0, stream>>>(weight, bias, Abuf);
    conv_kernel<<<NPLANES, 1024, LDS_BYTES, stream>>>(x, Abuf, out);
}

// Round 12
// 133.866 us; speedup vs baseline: 1.3813x; 1.0629x over previous
//
#include <hip/hip_runtime.h>
#include <math.h>

// Converse2D on gfx950 — spectral restructuring (R14):
//   out(2y+u, 2x+v) plane = ifft136( A_uv[g] * Xhat[g] ), per (n,c,u,v)
//   Xhat = rfft136x136(wrap_pad(x)); A_uv = per-channel multiplier (Hermitian).
// R14 (vs R13): conv is phase-LATENCY bound (five reorganizations all pinned
//   at 66-67us; conflict fix -2M cycles bought ~0 -> conflicts off critical
//   path). The inverse stage-2 phases run 552/544 items on 1024 threads
//   (2.2 waves/SIMD, no latency hiding, half the WG parked at the barrier).
//   FIX: split each float4 dual-plane dft17 item into TWO independent float2
//   half-items (.xy / .zw of the same elements): col-s2 552->1104 items,
//   ct68-s2 544->1088 items. Full WG active, waves/SIMD in these phases
//   doubles, per-thread regs halve. Everything else identical to R13.

#define MDIM 136
#define RSCF 146            // fwd float2 view: row stride (float2 units) = 2*RSC4
#define RSC4 73             // inverse float4 view: row stride (float4 units)
#define HC   69             // stored Hermitian half columns (0..68)
#define PLANE_HALF (MDIM*HC)   // 9384 per plane
#define NPLANES 256         // N*C
#define LDS_BYTES (MDIM*RSC4*16 + 306*8)   // plane + lutI/tI136/tI68 = 161,296 B
#define PI_D 3.14159265358979323846
#define NTH 1024

__device__ __forceinline__ int slot136(int k) { return 17*(k & 7) + (k >> 3); }
__device__ __forceinline__ int slot68(int k)  { return 17*(k & 3) + (k >> 2); }

// ---------- float4 "dual-complex" helpers: q = (re0, im0, re1, im1) ----------
__device__ __forceinline__ float4 q_add(float4 a, float4 b)
{ return make_float4(a.x+b.x, a.y+b.y, a.z+b.z, a.w+b.w); }
__device__ __forceinline__ float4 q_sub(float4 a, float4 b)
{ return make_float4(a.x-b.x, a.y-b.y, a.z-b.z, a.w-b.w); }
__device__ __forceinline__ float4 q_muli(float4 a, float d)   // d * (i*a), both halves
{ return make_float4(-d*a.y, d*a.x, -d*a.w, d*a.z); }
__device__ __forceinline__ float4 q_scale(float4 a, float s)
{ return make_float4(s*a.x, s*a.y, s*a.z, s*a.w); }
__device__ __forceinline__ float4 q_fma(float4 a, float s, float4 acc)
{ return make_float4(fmaf(a.x,s,acc.x), fmaf(a.y,s,acc.y),
                     fmaf(a.z,s,acc.z), fmaf(a.w,s,acc.w)); }
__device__ __forceinline__ float4 cmul4(float4 q, float2 w)   // same twiddle, both halves
{ return make_float4(q.x*w.x - q.y*w.y, q.x*w.y + q.y*w.x,
                     q.z*w.x - q.w*w.y, q.z*w.y + q.w*w.x); }

// ---------- symmetric 17-point DFT (float2), strided, sink outputs ----------
template<int DIR, class F>
__device__ __forceinline__ void dft17_sink(float2* z, int base, int stride, F f)
{
    constexpr float C17[9] = {1.f, 0.93247223f, 0.73900892f, 0.44573836f,
                              0.09226836f, -0.27366299f, -0.60263464f,
                              -0.85021714f, -0.98297310f};
    constexpr float S17[9] = {0.f, 0.36124167f, 0.67369564f, 0.89516329f,
                              0.99573418f, 0.96182564f, 0.79801723f,
                              0.52643216f, 0.18374952f};
    constexpr float d = (DIR > 0) ? 1.f : -1.f;
    float xr[17], xi[17];
#pragma unroll
    for (int n = 0; n < 17; n++) {
        float2 v = z[base + n*stride];
        xr[n] = v.x; xi[n] = v.y;
    }
    float ar[8], ai[8], br[8], bi[8];
#pragma unroll
    for (int n = 1; n <= 8; n++) {
        ar[n-1] = xr[n] + xr[17-n];  ai[n-1] = xi[n] + xi[17-n];
        br[n-1] = xr[n] - xr[17-n];  bi[n-1] = xi[n] - xi[17-n];
    }
    float s0r = xr[0], s0i = xi[0];
#pragma unroll
    for (int n = 0; n < 8; n++) { s0r += ar[n]; s0i += ai[n]; }
    f(0, s0r, s0i);
#pragma unroll
    for (int k = 1; k <= 8; k++) {
        float Pr = xr[0], Pi = xi[0], Qr = 0.f, Qi = 0.f;
#pragma unroll
        for (int n = 1; n <= 8; n++) {
            int m = (k*n) % 17;
            float cc = (m <= 8) ? C17[m] : C17[17-m];
            float ss = (m <= 8) ? S17[m] : -S17[17-m];
            Pr = fmaf(ar[n-1], cc, Pr);
            Pi = fmaf(ai[n-1], cc, Pi);
            Qr = fmaf(br[n-1], ss, Qr);
            Qi = fmaf(bi[n-1], ss, Qi);
        }
        f(k,    Pr - d*Qi, Pi + d*Qr);
        f(17-k, Pr + d*Qi, Pi - d*Qr);
    }
}

// ---------- radix-4 + table twiddle (float2; tables are INVERSE-dir, DIR<0 conj) ----------
template<int DIR>
__device__ __forceinline__ void radix4_tw(float2* z, const float2* t68, int base, int n2,
                                          float2 Z0, float2 Z1, float2 Z2, float2 Z3)
{
    constexpr float d = (DIR > 0) ? 1.0f : -1.0f;
    float t0r = Z0.x+Z2.x, t0i = Z0.y+Z2.y;
    float t1r = Z0.x-Z2.x, t1i = Z0.y-Z2.y;
    float t2r = Z1.x+Z3.x, t2i = Z1.y+Z3.y;
    float t3r = Z1.x-Z3.x, t3i = Z1.y-Z3.y;
    float X0r = t0r+t2r,     X0i = t0i+t2i;
    float X2r = t0r-t2r,     X2i = t0i-t2i;
    float X1r = t1r - d*t3i, X1i = t1i + d*t3r;
    float X3r = t1r + d*t3i, X3i = t1i - d*t3r;
    z[base + n2] = make_float2(X0r, X0i);
    float2 w1 = t68[n2], w2 = t68[17 + n2], w3 = t68[34 + n2];
    if (DIR < 0) { w1.y = -w1.y; w2.y = -w2.y; w3.y = -w3.y; }
    z[base + 17 + n2] = make_float2(X1r*w1.x - X1i*w1.y, X1r*w1.y + X1i*w1.x);
    z[base + 34 + n2] = make_float2(X2r*w2.x - X2i*w2.y, X2r*w2.y + X2i*w2.x);
    z[base + 51 + n2] = make_float2(X3r*w3.x - X3i*w3.y, X3r*w3.y + X3i*w3.x);
}

// ---------- radix-4 + table twiddle (float4 dual-plane, inverse only) ----------
template<int DIR>
__device__ __forceinline__ void radix4q_tw(float4* z, const float2* t68, int base, int n2,
                                           float4 Z0, float4 Z1, float4 Z2, float4 Z3)
{
    constexpr float d = (DIR > 0) ? 1.0f : -1.0f;
    float4 t0 = q_add(Z0, Z2), t1 = q_sub(Z0, Z2);
    float4 t2 = q_add(Z1, Z3), t3 = q_sub(Z1, Z3);
    float4 X0 = q_add(t0, t2), X2 = q_sub(t0, t2);
    float4 it3 = q_muli(t3, d);
    float4 X1 = q_add(t1, it3), X3 = q_sub(t1, it3);
    z[base + n2] = X0;
    float2 w1 = t68[n2], w2 = t68[17 + n2], w3 = t68[34 + n2];
    z[base + 17 + n2] = cmul4(X1, w1);
    z[base + 34 + n2] = cmul4(X2, w2);
    z[base + 51 + n2] = cmul4(X3, w3);
}

// ---------- 136-pt CT stage 1 (radix-8 + table twiddle), float2 fwd ----------
template<int DIR>
__device__ __forceinline__ void fft136_s1_body(float2* z, const float2* t136,
                                               int c, int n2)
{
    constexpr float d = (DIR > 0) ? 1.0f : -1.0f;
    constexpr float C707 = 0.70710678118654752f;
    float xr[8], xi[8];
#pragma unroll
    for (int n1 = 0; n1 < 8; n1++) {
        float2 v = z[(17*n1 + n2)*RSCF + c];
        xr[n1] = v.x; xi[n1] = v.y;
    }
    float e0r = xr[0]+xr[4], e0i = xi[0]+xi[4];
    float e1r = xr[0]-xr[4], e1i = xi[0]-xi[4];
    float o0r = xr[2]+xr[6], o0i = xi[2]+xi[6];
    float o1r = xr[2]-xr[6], o1i = xi[2]-xi[6];
    float E0r = e0r+o0r, E0i = e0i+o0i;
    float E2r = e0r-o0r, E2i = e0i-o0i;
    float E1r = e1r - d*o1i, E1i = e1i + d*o1r;
    float E3r = e1r + d*o1i, E3i = e1i - d*o1r;
    float f0r = xr[1]+xr[5], f0i = xi[1]+xi[5];
    float f1r = xr[1]-xr[5], f1i = xi[1]-xi[5];
    float h0r = xr[3]+xr[7], h0i = xi[3]+xi[7];
    float h1r = xr[3]-xr[7], h1i = xi[3]-xi[7];
    float O0r = f0r+h0r, O0i = f0i+h0i;
    float O2r = f0r-h0r, O2i = f0i-h0i;
    float O1r = f1r - d*h1i, O1i = f1i + d*h1r;
    float O3r = f1r + d*h1i, O3i = f1i - d*h1r;
    float t1r =  C707*(O1r - d*O1i), t1i = C707*(O1i + d*O1r);
    float t2r = -d*O2i,              t2i = d*O2r;
    float t3r = -C707*(O3r + d*O3i), t3i = C707*(d*O3r - O3i);
    float Xr[8], Xi[8];
    Xr[0]=E0r+O0r; Xi[0]=E0i+O0i;  Xr[4]=E0r-O0r; Xi[4]=E0i-O0i;
    Xr[1]=E1r+t1r; Xi[1]=E1i+t1i;  Xr[5]=E1r-t1r; Xi[5]=E1i-t1i;
    Xr[2]=E2r+t2r; Xi[2]=E2i+t2i;  Xr[6]=E2r-t2r; Xi[6]=E2i-t2i;
    Xr[3]=E3r+t3r; Xi[3]=E3i+t3i;  Xr[7]=E3r-t3r; Xi[7]=E3i-t3i;
    z[n2*RSCF + c] = make_float2(Xr[0], Xi[0]);
#pragma unroll
    for (int k1 = 1; k1 < 8; k1++) {
        float2 w = t136[(k1-1)*17 + n2];
        if (DIR < 0) w.y = -w.y;
        z[(17*k1 + n2)*RSCF + c] = make_float2(Xr[k1]*w.x - Xi[k1]*w.y,
                                               Xr[k1]*w.y + Xi[k1]*w.x);
    }
}

// ---------- 136-pt CT stage 1 (radix-8 + table twiddle), float4 dual-plane ----------
template<int DIR>
__device__ __forceinline__ void fft136q_s1_body(float4* z, const float2* t136,
                                                int c, int n2)
{
    constexpr float d = (DIR > 0) ? 1.0f : -1.0f;
    constexpr float C707 = 0.70710678118654752f;
    float4 x[8];
#pragma unroll
    for (int n1 = 0; n1 < 8; n1++) x[n1] = z[(17*n1 + n2)*RSC4 + c];
    float4 e0 = q_add(x[0], x[4]), e1 = q_sub(x[0], x[4]);
    float4 o0 = q_add(x[2], x[6]), o1 = q_sub(x[2], x[6]);
    float4 E0 = q_add(e0, o0), E2 = q_sub(e0, o0);
    float4 io1 = q_muli(o1, d);
    float4 E1 = q_add(e1, io1), E3 = q_sub(e1, io1);
    float4 f0 = q_add(x[1], x[5]), f1 = q_sub(x[1], x[5]);
    float4 h0 = q_add(x[3], x[7]), h1 = q_sub(x[3], x[7]);
    float4 O0 = q_add(f0, h0), O2 = q_sub(f0, h0);
    float4 ih1 = q_muli(h1, d);
    float4 O1 = q_add(f1, ih1), O3 = q_sub(f1, ih1);
    float4 t1 = q_scale(q_add(O1, q_muli(O1, d)), C707);
    float4 t2 = q_muli(O2, d);
    float4 t3 = q_scale(q_sub(O3, q_muli(O3, d)), -C707);
    float4 X0 = q_add(E0, O0), X4 = q_sub(E0, O0);
    float4 X1 = q_add(E1, t1), X5 = q_sub(E1, t1);
    float4 X2 = q_add(E2, t2), X6 = q_sub(E2, t2);
    float4 X3 = q_add(E3, t3), X7 = q_sub(E3, t3);
    z[n2*RSC4 + c] = X0;
    z[(17*1 + n2)*RSC4 + c] = cmul4(X1, t136[0*17 + n2]);
    z[(17*2 + n2)*RSC4 + c] = cmul4(X2, t136[1*17 + n2]);
    z[(17*3 + n2)*RSC4 + c] = cmul4(X3, t136[2*17 + n2]);
    z[(17*4 + n2)*RSC4 + c] = cmul4(X4, t136[3*17 + n2]);
    z[(17*5 + n2)*RSC4 + c] = cmul4(X5, t136[4*17 + n2]);
    z[(17*6 + n2)*RSC4 + c] = cmul4(X6, t136[5*17 + n2]);
    z[(17*7 + n2)*RSC4 + c] = cmul4(X7, t136[6*17 + n2]);
}

// c2r pack (float4 dual-plane), same w both halves.
__device__ __forceinline__ float4 c2r_pack4(float4 a, float4 b, float2 w)
{
    float Sx = a.x + b.x, Sy = a.y - b.y;
    float Dx = a.x - b.x, Dy = a.y + b.y;
    float Ox = w.x*Dx - w.y*Dy, Oy = w.x*Dy + w.y*Dx;
    float Sz = a.z + b.z, Sw = a.w - b.w;
    float Dz = a.z - b.z, Dw = a.w + b.w;
    float Oz = w.x*Dz - w.y*Dw, Ow = w.x*Dw + w.y*Dz;
    return make_float4(Sx - Oy, Sy + Ox, Sz - Ow, Sw + Oz);
}

// ---------- Fused forward + inverse: one WG per (n,c) plane (256 WGs) ----------
__global__ __launch_bounds__(1024, 4) void conv_kernel(const float* __restrict__ x,
                                                       const float4* __restrict__ Abuf,
                                                       float* __restrict__ out)
{
    extern __shared__ float4 z4s[];
    float4* z4    = z4s;                      // inverse: [136][73] dual-plane
    float2* zf    = (float2*)z4s;             // fwd view: row stride 146, cols 0..68
    float2* lutI  = (float2*)(z4s + MDIM*RSC4);   // exp(+2*pi*i*t/136)
    float2* tI136 = lutI + MDIM;              // [7][17]: w136^(k1*n2), inverse dir
    float2* tI68  = tI136 + 119;              // [3][17]: w68^((j+1)*n2), inverse dir
    const int tid = threadIdx.x;
    const int nc  = blockIdx.x;               // n*64 + c
    const int c   = nc & 63;

    if (tid < MDIM) {
        float s, cc; sincosf(2.0f*(float)PI_D*(float)tid/136.0f, &s, &cc);
        lutI[tid] = make_float2(cc, s);
    } else if (tid < MDIM + 119) {
        int it = tid - MDIM;
        int k1 = it/17 + 1, n2 = it - (it/17)*17;
        float s, cc; sincosf((float)(PI_D/68.0)*(float)(k1*n2), &s, &cc);
        tI136[it] = make_float2(cc, s);
    } else if (tid < MDIM + 119 + 51) {
        int it = tid - MDIM - 119;
        int j = it/17, n2 = it - 17*j;
        float s, cc; sincosf((float)(PI_D/34.0)*(float)((j+1)*n2), &s, &cc);
        tI68[it] = make_float2(cc, s);
    }
    // ---------------- forward on zf (stride RSCF) ----------------
    const float* xp = x + (size_t)nc * (128*128);
    {   // packed-row load: zf[i][n] = xp(i,2n) + i*xp(i,2n+1), wrap pad by 4
        int i = tid / 68, n = tid - (tid/68)*68;
        for (int e = tid; e < MDIM*68; e += NTH) {
            int si = (i + 124) & 127;
            int j0 = (2*n + 124) & 127;              // always even, pair never wraps
            zf[i*RSCF + n] = *reinterpret_cast<const float2*>(xp + si*128 + j0);
            i += 15; n += 4; if (n >= 68) { n -= 68; i++; }
        }
    }
    __syncthreads();
    {   // rows stage 1 (radix-4)
        int row = tid / 17;
        int n2  = tid - row*17;
        for (int e = tid; e < MDIM*17; e += NTH) {
            int base = row*RSCF;
            float2 Z0 = zf[base + n2];
            float2 Z1 = zf[base + 17 + n2];
            float2 Z2 = zf[base + 34 + n2];
            float2 Z3 = zf[base + 51 + n2];
            radix4_tw<-1>(zf, tI68, base, n2, Z0, Z1, Z2, Z3);
            row += 60; n2 += 4; if (n2 >= 17) { n2 -= 17; row++; }
        }
    }
    __syncthreads();
    if (tid < MDIM*4) {                              // rows stage 2: Z[k] at slot68(k)
        int row = tid >> 2, k1 = tid & 3;
        int base = row*RSCF + 17*k1;
        dft17_sink<-1>(zf, base, 1, [&](int k2, float re, float im) {
            zf[base + k2] = make_float2(re, im);
        });
    }
    __syncthreads();
    {   // r2c unpack: item k handles (k, 68-k), in-place at slots
        int row = tid / 35, k = tid - (tid/35)*35;
        for (int e = tid; e < MDIM*35; e += NTH) {
            int base = row*RSCF;
            int sa = slot68(k);
            float2 Za = zf[base+sa];
            float Zar = Za.x, Zai = Za.y;
            float Zbr, Zbi; int sb;
            if (k == 0) { Zbr = Zar; Zbi = Zai; sb = 68; }  // Z[68]==Z[0]; X[68]->col 68
            else {
                int kk = 68-k; sb = slot68(kk);
                float2 Zb = zf[base+sb]; Zbr = Zb.x; Zbi = Zb.y;
            }
            float2 w = lutI[k];                             // conj -> fwd w136^k
            float wc = w.x, ws = -w.y;
            float Er = 0.5f*(Zar + Zbr), Ei = 0.5f*(Zai - Zbi);
            float Dr = 0.5f*(Zar - Zbr), Di = 0.5f*(Zai + Zbi);
            float Tr = wc*Dr - ws*Di, Ti = wc*Di + ws*Dr;   // w^k * D
            zf[base+sa] = make_float2(Er + Ti, Ei - Tr);    // X[k] = E - i*(w^k D)
            float E2r = Er,  E2i = -Ei;
            float D2r = -Dr, D2i = Di;
            float w2c = -wc, w2s = ws;                      // w136^(68-k) = -conj(w^k)
            float T2r = w2c*D2r - w2s*D2i, T2i = w2c*D2i + w2s*D2r;
            zf[base+sb] = make_float2(E2r + T2i, E2i - T2r); // X[68-k]
            row += 29; k += 9; if (k >= 35) { k -= 35; row++; }
        }
    }
    __syncthreads();
    for (int e = tid; e < HC*17; e += NTH) {         // columns stage 1 (69 cols)
        int cc = (e*241) >> 12;                      // e/17, e <= 1172
        int n2 = e - cc*17;
        fft136_s1_body<-1>(zf, tI136, cc, n2);
    }
    __syncthreads();
    if (tid < HC*8) {                                // columns stage 2, in place
        int cc = tid >> 3, k1 = tid & 7;
        int base = 17*k1*RSCF + cc;
        dft17_sink<-1>(zf, base, RSCF, [&](int k2, float re, float im) {
            zf[base + k2*RSCF] = make_float2(re, im);
        });
    }
    __syncthreads();
    // ---------------- capture Xhat to registers ----------------
    float2 Xreg[10];
    {
        int g1 = tid / HC, g2 = tid - (tid/HC)*HC;
#pragma unroll
        for (int k = 0; k < 10; k++) {
            if (k < 9 || tid < PLANE_HALF - 9*NTH) {     // tail: 168 threads
                int cq = (g2 == 68) ? 68 : slot68(g2);
                Xreg[k] = zf[slot136(g1)*RSCF + cq];
            }
            g1 += 14; g2 += 58; if (g2 >= HC) { g2 -= HC; g1++; }
        }
    }
    __syncthreads();
    // ---------------- inverse, u = 0,1; both v-planes in z4 ----------------
    float* op = out + (size_t)nc * (256*256);
#pragma unroll 1
    for (int u = 0; u < 2; u++) {
        const float4* Ap = Abuf + (size_t)(c*2 + u) * PLANE_HALF;
        {   // S = A_uv * Xhat (both v), natural [g1][g2]; one 16B A-load/elem
            int g1 = tid / HC, g2 = tid - (tid/HC)*HC;
#pragma unroll
            for (int k = 0; k < 10; k++) {
                if (k < 9 || tid < PLANE_HALF - 9*NTH) {
                    float2 xv = Xreg[k];
                    float4 av = Ap[tid + k*NTH];
                    z4[g1*RSC4 + g2] = make_float4(
                        av.x*xv.x - av.y*xv.y, av.x*xv.y + av.y*xv.x,
                        av.z*xv.x - av.w*xv.y, av.z*xv.y + av.w*xv.x);
                }
                g1 += 14; g2 += 58; if (g2 >= HC) { g2 -= HC; g1++; }
            }
        }
        __syncthreads();
        // Columns stage 1: 69*17 = 1173 items, both planes per item.
        for (int e = tid; e < HC*17; e += NTH) {
            int cc = (e*241) >> 12;
            int n2 = e - cc*17;
            fft136q_s1_body<1>(z4, tI136, cc, n2);
        }
        __syncthreads();
        // Columns stage 2, SPLIT per v-half: 2*552 = 1104 float2 items
        // (was 552 float4 items on 1024 threads -> half the WG idle).
        {
            float2* z2 = (float2*)z4;
            for (int it = tid; it < 2*HC*8; it += NTH) {
                int half = it >= HC*8;
                int i  = it - (half ? HC*8 : 0);
                int cc = i >> 3, k1 = i & 7;
                int base = 2*(17*k1*RSC4 + cc) + half;
                dft17_sink<1>(z2, base, 2*RSC4, [&](int k2, float re, float im) {
                    z2[base + k2*2*RSC4] = make_float2(re, im);
                });
            }
        }
        __syncthreads();
        // Fused c2r pack + ct68 stage 1 (rows): 136*9 = 1224 items.
        for (int it = tid; it < MDIM*9; it += NTH) {
            int row = (it*7282) >> 16;                // it/9, it <= 1223
            int g   = it - row*9;
            int base = row*RSC4;
            if (g == 0) {
                float4 T0  = z4[base],    T17 = z4[base+17], T34 = z4[base+34],
                       T51 = z4[base+51], T68 = z4[base+68];
                float4 Z0 = c2r_pack4(T0,  T68, lutI[0]);
                float4 Z1 = c2r_pack4(T17, T51, lutI[17]);
                float4 Z2 = c2r_pack4(T34, T34, lutI[34]);
                float4 Z3 = c2r_pack4(T51, T17, lutI[51]);
                radix4q_tw<1>(z4, tI68, base, 0, Z0, Z1, Z2, Z3);
            } else {
                int gb = 17 - g;
                float4 Ta0 = z4[base+g],    Ta1 = z4[base+g+17],
                       Ta2 = z4[base+g+34], Ta3 = z4[base+g+51];
                float4 Tb0 = z4[base+gb],    Tb1 = z4[base+gb+17],
                       Tb2 = z4[base+gb+34], Tb3 = z4[base+gb+51];
                // partner of (g+17*n1) is (gb+17*(3-n1)), and vice versa
                float4 Za0 = c2r_pack4(Ta0, Tb3, lutI[g]);
                float4 Za1 = c2r_pack4(Ta1, Tb2, lutI[g+17]);
                float4 Za2 = c2r_pack4(Ta2, Tb1, lutI[g+34]);
                float4 Za3 = c2r_pack4(Ta3, Tb0, lutI[g+51]);
                float4 Zb0 = c2r_pack4(Tb0, Ta3, lutI[gb]);
                float4 Zb1 = c2r_pack4(Tb1, Ta2, lutI[gb+17]);
                float4 Zb2 = c2r_pack4(Tb2, Ta1, lutI[gb+34]);
                float4 Zb3 = c2r_pack4(Tb3, Ta0, lutI[gb+51]);
                radix4q_tw<1>(z4, tI68, base, g,  Za0, Za1, Za2, Za3);
                radix4q_tw<1>(z4, tI68, base, gb, Zb0, Zb1, Zb2, Zb3);
            }
        }
        __syncthreads();
        // ct68 stage 2, SPLIT per v-half: 2*544 = 1088 float2 items.
        {
            float2* z2 = (float2*)z4;
            for (int it = tid; it < 2*MDIM*4; it += NTH) {
                int half = it >= MDIM*4;
                int i   = it - (half ? MDIM*4 : 0);
                int row = i >> 2, k1 = i & 3;
                int base = 2*(row*RSC4 + 17*k1) + half;
                dft17_sink<1>(z2, base, 2, [&](int k2, float re, float im) {
                    z2[base + 2*k2] = make_float2(re, im);
                });
            }
        }
        __syncthreads();
        // Dense float4 store: one b128 read = the output quad
        // (re_v0, re_v1, im_v0, im_v1) at cols [4m-8..4m-5].
        {
            int m  = 2 + (tid & 63);          // [2,66)
            int y1 = 4 + (tid >> 6);          // [4,20); +16/iter -> [4,132)
            int a  = slot136(y1)*RSC4 + slot68(m);
            float* rowp = op + (size_t)(2*y1 + u - 8)*256 + 4*m - 8;
#pragma unroll
            for (int it = 0; it < 8; ++it) {
                float4 w = z4[a];
                *reinterpret_cast<float4*>(rowp) = make_float4(w.x, w.z, w.y, w.w);
                a += 2*RSC4;                  // slot136(y1+16) = slot136(y1) + 2
                rowp += 32*256;
            }
        }
        __syncthreads();                      // z4 reads done before next u writes
    }
}

// ---------- Per-channel multiplier precompute (f32, R table in LDS) ----------
// Output: Abuf[(c*2+u)*PLANE_HALF + e] = (M_{u,v=0}.re, .im, M_{u,v=1}.re, .im)
__global__ void prep_kernel(const float* __restrict__ weight,
                            const float* __restrict__ bias,
                            float4* __restrict__ Abuf)
{
    __shared__ float tabc[272], tabs[272];    // exp(-2*pi*i*t/272)
    __shared__ float Rs[69*5*4];              // (g2*5+a)*4 + {R0r,R0i,R1r,R1i}
    for (int t = threadIdx.x; t < 272; t += blockDim.x) {
        float s, c; sincosf(-2.0f*(float)PI_D*(float)t/272.0f, &s, &c);
        tabc[t] = c; tabs[t] = s;
    }
    const int c     = blockIdx.x >> 3;
    const int chunk = blockIdx.x & 7;
    const float* wp = weight + c*25;
    const float r = 1.0f/(1.0f + expf(9.0f - bias[c])) + 1e-5f;
    __syncthreads();
    // R precompute: R{0,1}[a][g2] = sum_b w[a][b] (+/-)^b e2[b](g2). 345 items.
    for (int it = threadIdx.x; it < 69*5; it += blockDim.x) {
        int g2 = it / 5, a = it - 5*g2;
        float c2 = tabc[g2], s2 = tabs[g2];
        float e2r[5], e2i[5];
        e2r[2]=1.0f; e2i[2]=0.0f; e2r[3]=c2; e2i[3]=s2;
        e2r[4]=c2*c2-s2*s2; e2i[4]=2.0f*c2*s2;
        e2r[1]=c2; e2i[1]=-s2; e2r[0]=e2r[4]; e2i[0]=-e2i[4];
        float w0=wp[a*5+0], w1=wp[a*5+1], w2=wp[a*5+2], w3=wp[a*5+3], w4=wp[a*5+4];
        float Rer = w0*e2r[0] + w2*e2r[2] + w4*e2r[4];
        float Rei = w0*e2i[0] + w2*e2i[2] + w4*e2i[4];
        float Ror = w1*e2r[1] + w3*e2r[3];
        float Roi = w1*e2i[1] + w3*e2i[3];
        Rs[it*4+0] = Rer + Ror;  Rs[it*4+1] = Rei + Roi;   // R0
        Rs[it*4+2] = Rer - Ror;  Rs[it*4+3] = Rei - Roi;   // R1
    }
    __syncthreads();

    const int e_lo = chunk * 1173;           // 8*1173 == PLANE_HALF
    const int e_hi = e_lo + 1173;
    int e  = e_lo + (int)threadIdx.x;
    int g1 = e / HC, g2 = e - (e/HC)*HC;
    for (; e < e_hi; e += blockDim.x) {
        float c1 = tabc[g1], s1 = tabs[g1];
        float e1r[5], e1i[5];
        e1r[2]=1.0f; e1i[2]=0.0f; e1r[3]=c1; e1i[3]=s1;
        e1r[4]=c1*c1-s1*s1; e1i[4]=2.0f*c1*s1;
        e1r[1]=c1; e1i[1]=-s1; e1r[0]=e1r[4]; e1i[0]=-e1i[4];

        // FB[a1][b1] = sum_a (+/-)^(a*a1) e1[a] * R[b1][a], via even/odd-a split.
        float FBr[2][2], FBi[2][2];
#pragma unroll
        for (int b1 = 0; b1 < 2; b1++) {
            float Per=0.f, Pei=0.f, Por=0.f, Poi=0.f;
#pragma unroll
            for (int a = 0; a < 5; a++) {
                float Rr = Rs[(g2*5+a)*4 + 2*b1];
                float Ri = Rs[(g2*5+a)*4 + 2*b1 + 1];
                float tr = e1r[a]*Rr - e1i[a]*Ri;
                float ti = e1r[a]*Ri + e1i[a]*Rr;
                if (a & 1) { Por += tr; Poi += ti; } else { Per += tr; Pei += ti; }
            }
            FBr[0][b1] = Per + Por;  FBi[0][b1] = Pei + Poi;
            FBr[1][b1] = Per - Por;  FBi[1][b1] = Pei - Poi;
        }
        float c2 = tabc[g2], s2 = tabs[g2];
        float ur[2]={1.0f+c1, 1.0f-c1}, ui[2]={s1, -s1};
        float vr[2]={1.0f+c2, 1.0f-c2}, vi[2]={s2, -s2};
        float Br_[2][2], Bi_[2][2];
#pragma unroll
        for (int a1 = 0; a1 < 2; a1++)
#pragma unroll
            for (int b1 = 0; b1 < 2; b1++) {
                Br_[a1][b1] = ur[a1]*vr[b1] - ui[a1]*vi[b1];
                Bi_[a1][b1] = ur[a1]*vi[b1] + ui[a1]*vr[b1];
            }
        float invW=0.f, Qr=0.f, Qi=0.f;
#pragma unroll
        for (int a1 = 0; a1 < 2; a1++)
#pragma unroll
            for (int b1 = 0; b1 < 2; b1++) {
                invW += FBr[a1][b1]*FBr[a1][b1] + FBi[a1][b1]*FBi[a1][b1];
                Qr += FBr[a1][b1]*Br_[a1][b1] - FBi[a1][b1]*Bi_[a1][b1];
                Qi += FBr[a1][b1]*Bi_[a1][b1] + FBi[a1][b1]*Br_[a1][b1];
            }
        invW *= 0.25f; Qr *= 0.25f; Qi *= 0.25f;
        float den = 1.0f/(invW + r);
        float Sr = (1.0f - Qr)*den, Si = -Qi*den;
        float Mr[2][2], Mi[2][2];
#pragma unroll
        for (int a1 = 0; a1 < 2; a1++)
#pragma unroll
            for (int b1 = 0; b1 < 2; b1++) {
                Mr[a1][b1] = Br_[a1][b1] + FBr[a1][b1]*Sr + FBi[a1][b1]*Si;
                Mi[a1][b1] = Bi_[a1][b1] + FBr[a1][b1]*Si - FBi[a1][b1]*Sr;
            }
        const float scale = 1.0f/73984.0f;   // 1/272^2 ifft normalization
#pragma unroll
        for (int uu = 0; uu < 2; uu++) {
            float ov[4];
#pragma unroll
            for (int vv = 0; vv < 2; vv++) {
                float sr=0.f, si=0.f;
#pragma unroll
                for (int a1 = 0; a1 < 2; a1++)
#pragma unroll
                    for (int b1 = 0; b1 < 2; b1++) {
                        if ((a1*uu + b1*vv) & 1) { sr -= Mr[a1][b1]; si -= Mi[a1][b1]; }
                        else                     { sr += Mr[a1][b1]; si += Mi[a1][b1]; }
                    }
                int t = g1*uu + g2*vv;                 // <= 203 < 272
                float pc = tabc[t], ps = -tabs[t];     // exp(+i*pi*t/136)
                ov[2*vv]   = (pc*sr - ps*si)*scale;
                ov[2*vv+1] = (pc*si + ps*sr)*scale;
            }
            Abuf[((size_t)(c*2 + uu))*PLANE_HALF + e] =
                make_float4(ov[0], ov[1], ov[2], ov[3]);
        }
        g1 += 3; g2 += 49; if (g2 >= HC) { g2 -= HC; g1++; }   // e += 256
    }
}

extern "C" void kernel_launch(void* const* d_in, const int* in_sizes, int n_in,
                              void* d_out, int out_size, void* d_ws, size_t ws_size,
                              hipStream_t stream)
{
    const float* x      = (const float*)d_in[0];
    const float* weight = (const float*)d_in[1];
    const float* bias   = (const float*)d_in[2];
    float* out = (float*)d_out;

    float4* Abuf = (float4*)d_ws;     // 128 * 9384 * 16B = 19.2 MB

    (void)hipFuncSetAttribute((const void*)conv_kernel,
                              hipFuncAttributeMaxDynamicSharedMemorySize,
                              (int)LDS_BYTES);

    prep_kernel<<<512, 256, 0, stream>>>(weight, bias, Abuf);
    conv_kernel<<<NPLANES, 1024, LDS_BYTES, stream>>>(x, Abuf, out);
}

// Round 13
// 130.974 us; speedup vs baseline: 1.4118x; 1.0221x over previous
//
#include <hip/hip_runtime.h>
#include <math.h>

// Converse2D on gfx950 — spectral restructuring (R15):
//   out(2y+u, 2x+v) plane = ifft136( A_uv[g] * Xhat[g] ), per (n,c,u,v)
//   Xhat = rfft136x136(wrap_pad(x)); A_uv = per-channel multiplier (Hermitian).
// R15 (vs R14): R14's stage-2 v-half split (66.4->61us) put its b64 accesses
//   at (2*(k1+cc)+half) mod 16 pair-banks with half CONSTANT per wave-block:
//   64 lanes on 8 even pair-banks = 8-way serialization ON the latency-critical
//   dft17 chains (SQ_LDS_BANK_CONFLICT 4.28M->7.76M). FIX: half = it&1 (bit 0)
//   so adjacent lanes alternate halves -> 4 lanes/pair-bank, conflict-free b64.
//   Identical work; pure lane->bank remap in the two split phases.

#define MDIM 136
#define RSCF 146            // fwd float2 view: row stride (float2 units) = 2*RSC4
#define RSC4 73             // inverse float4 view: row stride (float4 units)
#define HC   69             // stored Hermitian half columns (0..68)
#define PLANE_HALF (MDIM*HC)   // 9384 per plane
#define NPLANES 256         // N*C
#define LDS_BYTES (MDIM*RSC4*16 + 306*8)   // plane + lutI/tI136/tI68 = 161,296 B
#define PI_D 3.14159265358979323846
#define NTH 1024

__device__ __forceinline__ int slot136(int k) { return 17*(k & 7) + (k >> 3); }
__device__ __forceinline__ int slot68(int k)  { return 17*(k & 3) + (k >> 2); }

// ---------- float4 "dual-complex" helpers: q = (re0, im0, re1, im1) ----------
__device__ __forceinline__ float4 q_add(float4 a, float4 b)
{ return make_float4(a.x+b.x, a.y+b.y, a.z+b.z, a.w+b.w); }
__device__ __forceinline__ float4 q_sub(float4 a, float4 b)
{ return make_float4(a.x-b.x, a.y-b.y, a.z-b.z, a.w-b.w); }
__device__ __forceinline__ float4 q_muli(float4 a, float d)   // d * (i*a), both halves
{ return make_float4(-d*a.y, d*a.x, -d*a.w, d*a.z); }
__device__ __forceinline__ float4 q_scale(float4 a, float s)
{ return make_float4(s*a.x, s*a.y, s*a.z, s*a.w); }
__device__ __forceinline__ float4 q_fma(float4 a, float s, float4 acc)
{ return make_float4(fmaf(a.x,s,acc.x), fmaf(a.y,s,acc.y),
                     fmaf(a.z,s,acc.z), fmaf(a.w,s,acc.w)); }
__device__ __forceinline__ float4 cmul4(float4 q, float2 w)   // same twiddle, both halves
{ return make_float4(q.x*w.x - q.y*w.y, q.x*w.y + q.y*w.x,
                     q.z*w.x - q.w*w.y, q.z*w.y + q.w*w.x); }

// ---------- symmetric 17-point DFT (float2), strided, sink outputs ----------
template<int DIR, class F>
__device__ __forceinline__ void dft17_sink(float2* z, int base, int stride, F f)
{
    constexpr float C17[9] = {1.f, 0.93247223f, 0.73900892f, 0.44573836f,
                              0.09226836f, -0.27366299f, -0.60263464f,
                              -0.85021714f, -0.98297310f};
    constexpr float S17[9] = {0.f, 0.36124167f, 0.67369564f, 0.89516329f,
                              0.99573418f, 0.96182564f, 0.79801723f,
                              0.52643216f, 0.18374952f};
    constexpr float d = (DIR > 0) ? 1.f : -1.f;
    float xr[17], xi[17];
#pragma unroll
    for (int n = 0; n < 17; n++) {
        float2 v = z[base + n*stride];
        xr[n] = v.x; xi[n] = v.y;
    }
    float ar[8], ai[8], br[8], bi[8];
#pragma unroll
    for (int n = 1; n <= 8; n++) {
        ar[n-1] = xr[n] + xr[17-n];  ai[n-1] = xi[n] + xi[17-n];
        br[n-1] = xr[n] - xr[17-n];  bi[n-1] = xi[n] - xi[17-n];
    }
    float s0r = xr[0], s0i = xi[0];
#pragma unroll
    for (int n = 0; n < 8; n++) { s0r += ar[n]; s0i += ai[n]; }
    f(0, s0r, s0i);
#pragma unroll
    for (int k = 1; k <= 8; k++) {
        float Pr = xr[0], Pi = xi[0], Qr = 0.f, Qi = 0.f;
#pragma unroll
        for (int n = 1; n <= 8; n++) {
            int m = (k*n) % 17;
            float cc = (m <= 8) ? C17[m] : C17[17-m];
            float ss = (m <= 8) ? S17[m] : -S17[17-m];
            Pr = fmaf(ar[n-1], cc, Pr);
            Pi = fmaf(ai[n-1], cc, Pi);
            Qr = fmaf(br[n-1], ss, Qr);
            Qi = fmaf(bi[n-1], ss, Qi);
        }
        f(k,    Pr - d*Qi, Pi + d*Qr);
        f(17-k, Pr + d*Qi, Pi - d*Qr);
    }
}

// ---------- radix-4 + table twiddle (float2; tables are INVERSE-dir, DIR<0 conj) ----------
template<int DIR>
__device__ __forceinline__ void radix4_tw(float2* z, const float2* t68, int base, int n2,
                                          float2 Z0, float2 Z1, float2 Z2, float2 Z3)
{
    constexpr float d = (DIR > 0) ? 1.0f : -1.0f;
    float t0r = Z0.x+Z2.x, t0i = Z0.y+Z2.y;
    float t1r = Z0.x-Z2.x, t1i = Z0.y-Z2.y;
    float t2r = Z1.x+Z3.x, t2i = Z1.y+Z3.y;
    float t3r = Z1.x-Z3.x, t3i = Z1.y-Z3.y;
    float X0r = t0r+t2r,     X0i = t0i+t2i;
    float X2r = t0r-t2r,     X2i = t0i-t2i;
    float X1r = t1r - d*t3i, X1i = t1i + d*t3r;
    float X3r = t1r + d*t3i, X3i = t1i - d*t3r;
    z[base + n2] = make_float2(X0r, X0i);
    float2 w1 = t68[n2], w2 = t68[17 + n2], w3 = t68[34 + n2];
    if (DIR < 0) { w1.y = -w1.y; w2.y = -w2.y; w3.y = -w3.y; }
    z[base + 17 + n2] = make_float2(X1r*w1.x - X1i*w1.y, X1r*w1.y + X1i*w1.x);
    z[base + 34 + n2] = make_float2(X2r*w2.x - X2i*w2.y, X2r*w2.y + X2i*w2.x);
    z[base + 51 + n2] = make_float2(X3r*w3.x - X3i*w3.y, X3r*w3.y + X3i*w3.x);
}

// ---------- radix-4 + table twiddle (float4 dual-plane, inverse only) ----------
template<int DIR>
__device__ __forceinline__ void radix4q_tw(float4* z, const float2* t68, int base, int n2,
                                           float4 Z0, float4 Z1, float4 Z2, float4 Z3)
{
    constexpr float d = (DIR > 0) ? 1.0f : -1.0f;
    float4 t0 = q_add(Z0, Z2), t1 = q_sub(Z0, Z2);
    float4 t2 = q_add(Z1, Z3), t3 = q_sub(Z1, Z3);
    float4 X0 = q_add(t0, t2), X2 = q_sub(t0, t2);
    float4 it3 = q_muli(t3, d);
    float4 X1 = q_add(t1, it3), X3 = q_sub(t1, it3);
    z[base + n2] = X0;
    float2 w1 = t68[n2], w2 = t68[17 + n2], w3 = t68[34 + n2];
    z[base + 17 + n2] = cmul4(X1, w1);
    z[base + 34 + n2] = cmul4(X2, w2);
    z[base + 51 + n2] = cmul4(X3, w3);
}

// ---------- 136-pt CT stage 1 (radix-8 + table twiddle), float2 fwd ----------
template<int DIR>
__device__ __forceinline__ void fft136_s1_body(float2* z, const float2* t136,
                                               int c, int n2)
{
    constexpr float d = (DIR > 0) ? 1.0f : -1.0f;
    constexpr float C707 = 0.70710678118654752f;
    float xr[8], xi[8];
#pragma unroll
    for (int n1 = 0; n1 < 8; n1++) {
        float2 v = z[(17*n1 + n2)*RSCF + c];
        xr[n1] = v.x; xi[n1] = v.y;
    }
    float e0r = xr[0]+xr[4], e0i = xi[0]+xi[4];
    float e1r = xr[0]-xr[4], e1i = xi[0]-xi[4];
    float o0r = xr[2]+xr[6], o0i = xi[2]+xi[6];
    float o1r = xr[2]-xr[6], o1i = xi[2]-xi[6];
    float E0r = e0r+o0r, E0i = e0i+o0i;
    float E2r = e0r-o0r, E2i = e0i-o0i;
    float E1r = e1r - d*o1i, E1i = e1i + d*o1r;
    float E3r = e1r + d*o1i, E3i = e1i - d*o1r;
    float f0r = xr[1]+xr[5], f0i = xi[1]+xi[5];
    float f1r = xr[1]-xr[5], f1i = xi[1]-xi[5];
    float h0r = xr[3]+xr[7], h0i = xi[3]+xi[7];
    float h1r = xr[3]-xr[7], h1i = xi[3]-xi[7];
    float O0r = f0r+h0r, O0i = f0i+h0i;
    float O2r = f0r-h0r, O2i = f0i-h0i;
    float O1r = f1r - d*h1i, O1i = f1i + d*h1r;
    float O3r = f1r + d*h1i, O3i = f1i - d*h1r;
    float t1r =  C707*(O1r - d*O1i), t1i = C707*(O1i + d*O1r);
    float t2r = -d*O2i,              t2i = d*O2r;
    float t3r = -C707*(O3r + d*O3i), t3i = C707*(d*O3r - O3i);
    float Xr[8], Xi[8];
    Xr[0]=E0r+O0r; Xi[0]=E0i+O0i;  Xr[4]=E0r-O0r; Xi[4]=E0i-O0i;
    Xr[1]=E1r+t1r; Xi[1]=E1i+t1i;  Xr[5]=E1r-t1r; Xi[5]=E1i-t1i;
    Xr[2]=E2r+t2r; Xi[2]=E2i+t2i;  Xr[6]=E2r-t2r; Xi[6]=E2i-t2i;
    Xr[3]=E3r+t3r; Xi[3]=E3i+t3i;  Xr[7]=E3r-t3r; Xi[7]=E3i-t3i;
    z[n2*RSCF + c] = make_float2(Xr[0], Xi[0]);
#pragma unroll
    for (int k1 = 1; k1 < 8; k1++) {
        float2 w = t136[(k1-1)*17 + n2];
        if (DIR < 0) w.y = -w.y;
        z[(17*k1 + n2)*RSCF + c] = make_float2(Xr[k1]*w.x - Xi[k1]*w.y,
                                               Xr[k1]*w.y + Xi[k1]*w.x);
    }
}

// ---------- 136-pt CT stage 1 (radix-8 + table twiddle), float4 dual-plane ----------
template<int DIR>
__device__ __forceinline__ void fft136q_s1_body(float4* z, const float2* t136,
                                                int c, int n2)
{
    constexpr float d = (DIR > 0) ? 1.0f : -1.0f;
    constexpr float C707 = 0.70710678118654752f;
    float4 x[8];
#pragma unroll
    for (int n1 = 0; n1 < 8; n1++) x[n1] = z[(17*n1 + n2)*RSC4 + c];
    float4 e0 = q_add(x[0], x[4]), e1 = q_sub(x[0], x[4]);
    float4 o0 = q_add(x[2], x[6]), o1 = q_sub(x[2], x[6]);
    float4 E0 = q_add(e0, o0), E2 = q_sub(e0, o0);
    float4 io1 = q_muli(o1, d);
    float4 E1 = q_add(e1, io1), E3 = q_sub(e1, io1);
    float4 f0 = q_add(x[1], x[5]), f1 = q_sub(x[1], x[5]);
    float4 h0 = q_add(x[3], x[7]), h1 = q_sub(x[3], x[7]);
    float4 O0 = q_add(f0, h0), O2 = q_sub(f0, h0);
    float4 ih1 = q_muli(h1, d);
    float4 O1 = q_add(f1, ih1), O3 = q_sub(f1, ih1);
    float4 t1 = q_scale(q_add(O1, q_muli(O1, d)), C707);
    float4 t2 = q_muli(O2, d);
    float4 t3 = q_scale(q_sub(O3, q_muli(O3, d)), -C707);
    float4 X0 = q_add(E0, O0), X4 = q_sub(E0, O0);
    float4 X1 = q_add(E1, t1), X5 = q_sub(E1, t1);
    float4 X2 = q_add(E2, t2), X6 = q_sub(E2, t2);
    float4 X3 = q_add(E3, t3), X7 = q_sub(E3, t3);
    z[n2*RSC4 + c] = X0;
    z[(17*1 + n2)*RSC4 + c] = cmul4(X1, t136[0*17 + n2]);
    z[(17*2 + n2)*RSC4 + c] = cmul4(X2, t136[1*17 + n2]);
    z[(17*3 + n2)*RSC4 + c] = cmul4(X3, t136[2*17 + n2]);
    z[(17*4 + n2)*RSC4 + c] = cmul4(X4, t136[3*17 + n2]);
    z[(17*5 + n2)*RSC4 + c] = cmul4(X5, t136[4*17 + n2]);
    z[(17*6 + n2)*RSC4 + c] = cmul4(X6, t136[5*17 + n2]);
    z[(17*7 + n2)*RSC4 + c] = cmul4(X7, t136[6*17 + n2]);
}

// c2r pack (float4 dual-plane), same w both halves.
__device__ __forceinline__ float4 c2r_pack4(float4 a, float4 b, float2 w)
{
    float Sx = a.x + b.x, Sy = a.y - b.y;
    float Dx = a.x - b.x, Dy = a.y + b.y;
    float Ox = w.x*Dx - w.y*Dy, Oy = w.x*Dy + w.y*Dx;
    float Sz = a.z + b.z, Sw = a.w - b.w;
    float Dz = a.z - b.z, Dw = a.w + b.w;
    float Oz = w.x*Dz - w.y*Dw, Ow = w.x*Dw + w.y*Dz;
    return make_float4(Sx - Oy, Sy + Ox, Sz - Ow, Sw + Oz);
}

// ---------- Fused forward + inverse: one WG per (n,c) plane (256 WGs) ----------
__global__ __launch_bounds__(1024, 4) void conv_kernel(const float* __restrict__ x,
                                                       const float4* __restrict__ Abuf,
                                                       float* __restrict__ out)
{
    extern __shared__ float4 z4s[];
    float4* z4    = z4s;                      // inverse: [136][73] dual-plane
    float2* zf    = (float2*)z4s;             // fwd view: row stride 146, cols 0..68
    float2* lutI  = (float2*)(z4s + MDIM*RSC4);   // exp(+2*pi*i*t/136)
    float2* tI136 = lutI + MDIM;              // [7][17]: w136^(k1*n2), inverse dir
    float2* tI68  = tI136 + 119;              // [3][17]: w68^((j+1)*n2), inverse dir
    const int tid = threadIdx.x;
    const int nc  = blockIdx.x;               // n*64 + c
    const int c   = nc & 63;

    if (tid < MDIM) {
        float s, cc; sincosf(2.0f*(float)PI_D*(float)tid/136.0f, &s, &cc);
        lutI[tid] = make_float2(cc, s);
    } else if (tid < MDIM + 119) {
        int it = tid - MDIM;
        int k1 = it/17 + 1, n2 = it - (it/17)*17;
        float s, cc; sincosf((float)(PI_D/68.0)*(float)(k1*n2), &s, &cc);
        tI136[it] = make_float2(cc, s);
    } else if (tid < MDIM + 119 + 51) {
        int it = tid - MDIM - 119;
        int j = it/17, n2 = it - 17*j;
        float s, cc; sincosf((float)(PI_D/34.0)*(float)((j+1)*n2), &s, &cc);
        tI68[it] = make_float2(cc, s);
    }
    // ---------------- forward on zf (stride RSCF) ----------------
    const float* xp = x + (size_t)nc * (128*128);
    {   // packed-row load: zf[i][n] = xp(i,2n) + i*xp(i,2n+1), wrap pad by 4
        int i = tid / 68, n = tid - (tid/68)*68;
        for (int e = tid; e < MDIM*68; e += NTH) {
            int si = (i + 124) & 127;
            int j0 = (2*n + 124) & 127;              // always even, pair never wraps
            zf[i*RSCF + n] = *reinterpret_cast<const float2*>(xp + si*128 + j0);
            i += 15; n += 4; if (n >= 68) { n -= 68; i++; }
        }
    }
    __syncthreads();
    {   // rows stage 1 (radix-4)
        int row = tid / 17;
        int n2  = tid - row*17;
        for (int e = tid; e < MDIM*17; e += NTH) {
            int base = row*RSCF;
            float2 Z0 = zf[base + n2];
            float2 Z1 = zf[base + 17 + n2];
            float2 Z2 = zf[base + 34 + n2];
            float2 Z3 = zf[base + 51 + n2];
            radix4_tw<-1>(zf, tI68, base, n2, Z0, Z1, Z2, Z3);
            row += 60; n2 += 4; if (n2 >= 17) { n2 -= 17; row++; }
        }
    }
    __syncthreads();
    if (tid < MDIM*4) {                              // rows stage 2: Z[k] at slot68(k)
        int row = tid >> 2, k1 = tid & 3;
        int base = row*RSCF + 17*k1;
        dft17_sink<-1>(zf, base, 1, [&](int k2, float re, float im) {
            zf[base + k2] = make_float2(re, im);
        });
    }
    __syncthreads();
    {   // r2c unpack: item k handles (k, 68-k), in-place at slots
        int row = tid / 35, k = tid - (tid/35)*35;
        for (int e = tid; e < MDIM*35; e += NTH) {
            int base = row*RSCF;
            int sa = slot68(k);
            float2 Za = zf[base+sa];
            float Zar = Za.x, Zai = Za.y;
            float Zbr, Zbi; int sb;
            if (k == 0) { Zbr = Zar; Zbi = Zai; sb = 68; }  // Z[68]==Z[0]; X[68]->col 68
            else {
                int kk = 68-k; sb = slot68(kk);
                float2 Zb = zf[base+sb]; Zbr = Zb.x; Zbi = Zb.y;
            }
            float2 w = lutI[k];                             // conj -> fwd w136^k
            float wc = w.x, ws = -w.y;
            float Er = 0.5f*(Zar + Zbr), Ei = 0.5f*(Zai - Zbi);
            float Dr = 0.5f*(Zar - Zbr), Di = 0.5f*(Zai + Zbi);
            float Tr = wc*Dr - ws*Di, Ti = wc*Di + ws*Dr;   // w^k * D
            zf[base+sa] = make_float2(Er + Ti, Ei - Tr);    // X[k] = E - i*(w^k D)
            float E2r = Er,  E2i = -Ei;
            float D2r = -Dr, D2i = Di;
            float w2c = -wc, w2s = ws;                      // w136^(68-k) = -conj(w^k)
            float T2r = w2c*D2r - w2s*D2i, T2i = w2c*D2i + w2s*D2r;
            zf[base+sb] = make_float2(E2r + T2i, E2i - T2r); // X[68-k]
            row += 29; k += 9; if (k >= 35) { k -= 35; row++; }
        }
    }
    __syncthreads();
    for (int e = tid; e < HC*17; e += NTH) {         // columns stage 1 (69 cols)
        int cc = (e*241) >> 12;                      // e/17, e <= 1172
        int n2 = e - cc*17;
        fft136_s1_body<-1>(zf, tI136, cc, n2);
    }
    __syncthreads();
    if (tid < HC*8) {                                // columns stage 2, in place
        int cc = tid >> 3, k1 = tid & 7;
        int base = 17*k1*RSCF + cc;
        dft17_sink<-1>(zf, base, RSCF, [&](int k2, float re, float im) {
            zf[base + k2*RSCF] = make_float2(re, im);
        });
    }
    __syncthreads();
    // ---------------- capture Xhat to registers ----------------
    float2 Xreg[10];
    {
        int g1 = tid / HC, g2 = tid - (tid/HC)*HC;
#pragma unroll
        for (int k = 0; k < 10; k++) {
            if (k < 9 || tid < PLANE_HALF - 9*NTH) {     // tail: 168 threads
                int cq = (g2 == 68) ? 68 : slot68(g2);
                Xreg[k] = zf[slot136(g1)*RSCF + cq];
            }
            g1 += 14; g2 += 58; if (g2 >= HC) { g2 -= HC; g1++; }
        }
    }
    __syncthreads();
    // ---------------- inverse, u = 0,1; both v-planes in z4 ----------------
    float* op = out + (size_t)nc * (256*256);
#pragma unroll 1
    for (int u = 0; u < 2; u++) {
        const float4* Ap = Abuf + (size_t)(c*2 + u) * PLANE_HALF;
        {   // S = A_uv * Xhat (both v), natural [g1][g2]; one 16B A-load/elem
            int g1 = tid / HC, g2 = tid - (tid/HC)*HC;
#pragma unroll
            for (int k = 0; k < 10; k++) {
                if (k < 9 || tid < PLANE_HALF - 9*NTH) {
                    float2 xv = Xreg[k];
                    float4 av = Ap[tid + k*NTH];
                    z4[g1*RSC4 + g2] = make_float4(
                        av.x*xv.x - av.y*xv.y, av.x*xv.y + av.y*xv.x,
                        av.z*xv.x - av.w*xv.y, av.z*xv.y + av.w*xv.x);
                }
                g1 += 14; g2 += 58; if (g2 >= HC) { g2 -= HC; g1++; }
            }
        }
        __syncthreads();
        // Columns stage 1: 69*17 = 1173 items, both planes per item.
        for (int e = tid; e < HC*17; e += NTH) {
            int cc = (e*241) >> 12;
            int n2 = e - cc*17;
            fft136q_s1_body<1>(z4, tI136, cc, n2);
        }
        __syncthreads();
        // Columns stage 2, split per v-half with half = bit 0 (bank-interleaved):
        // pair-bank = (2*(k1+cc) + half) mod 16 -> 4 lanes/bank, conflict-free.
        {
            float2* z2 = (float2*)z4;
            for (int it = tid; it < 2*HC*8; it += NTH) {
                int half = it & 1;
                int i  = it >> 1;                     // 0..551
                int cc = i >> 3, k1 = i & 7;
                int base = 2*(17*k1*RSC4 + cc) + half;
                dft17_sink<1>(z2, base, 2*RSC4, [&](int k2, float re, float im) {
                    z2[base + k2*2*RSC4] = make_float2(re, im);
                });
            }
        }
        __syncthreads();
        // Fused c2r pack + ct68 stage 1 (rows): 136*9 = 1224 items.
        for (int it = tid; it < MDIM*9; it += NTH) {
            int row = (it*7282) >> 16;                // it/9, it <= 1223
            int g   = it - row*9;
            int base = row*RSC4;
            if (g == 0) {
                float4 T0  = z4[base],    T17 = z4[base+17], T34 = z4[base+34],
                       T51 = z4[base+51], T68 = z4[base+68];
                float4 Z0 = c2r_pack4(T0,  T68, lutI[0]);
                float4 Z1 = c2r_pack4(T17, T51, lutI[17]);
                float4 Z2 = c2r_pack4(T34, T34, lutI[34]);
                float4 Z3 = c2r_pack4(T51, T17, lutI[51]);
                radix4q_tw<1>(z4, tI68, base, 0, Z0, Z1, Z2, Z3);
            } else {
                int gb = 17 - g;
                float4 Ta0 = z4[base+g],    Ta1 = z4[base+g+17],
                       Ta2 = z4[base+g+34], Ta3 = z4[base+g+51];
                float4 Tb0 = z4[base+gb],    Tb1 = z4[base+gb+17],
                       Tb2 = z4[base+gb+34], Tb3 = z4[base+gb+51];
                // partner of (g+17*n1) is (gb+17*(3-n1)), and vice versa
                float4 Za0 = c2r_pack4(Ta0, Tb3, lutI[g]);
                float4 Za1 = c2r_pack4(Ta1, Tb2, lutI[g+17]);
                float4 Za2 = c2r_pack4(Ta2, Tb1, lutI[g+34]);
                float4 Za3 = c2r_pack4(Ta3, Tb0, lutI[g+51]);
                float4 Zb0 = c2r_pack4(Tb0, Ta3, lutI[gb]);
                float4 Zb1 = c2r_pack4(Tb1, Ta2, lutI[gb+17]);
                float4 Zb2 = c2r_pack4(Tb2, Ta1, lutI[gb+34]);
                float4 Zb3 = c2r_pack4(Tb3, Ta0, lutI[gb+51]);
                radix4q_tw<1>(z4, tI68, base, g,  Za0, Za1, Za2, Za3);
                radix4q_tw<1>(z4, tI68, base, gb, Zb0, Zb1, Zb2, Zb3);
            }
        }
        __syncthreads();
        // ct68 stage 2, split per v-half with half = bit 0 (bank-interleaved):
        // pair-bank = (2*(row+k1) + half) mod 16 -> 4 lanes/bank, conflict-free.
        {
            float2* z2 = (float2*)z4;
            for (int it = tid; it < 2*MDIM*4; it += NTH) {
                int half = it & 1;
                int i   = it >> 1;                    // 0..543
                int row = i >> 2, k1 = i & 3;
                int base = 2*(row*RSC4 + 17*k1) + half;
                dft17_sink<1>(z2, base, 2, [&](int k2, float re, float im) {
                    z2[base + 2*k2] = make_float2(re, im);
                });
            }
        }
        __syncthreads();
        // Dense float4 store: one b128 read = the output quad
        // (re_v0, re_v1, im_v0, im_v1) at cols [4m-8..4m-5].
        {
            int m  = 2 + (tid & 63);          // [2,66)
            int y1 = 4 + (tid >> 6);          // [4,20); +16/iter -> [4,132)
            int a  = slot136(y1)*RSC4 + slot68(m);
            float* rowp = op + (size_t)(2*y1 + u - 8)*256 + 4*m - 8;
#pragma unroll
            for (int it = 0; it < 8; ++it) {
                float4 w = z4[a];
                *reinterpret_cast<float4*>(rowp) = make_float4(w.x, w.z, w.y, w.w);
                a += 2*RSC4;                  // slot136(y1+16) = slot136(y1) + 2
                rowp += 32*256;
            }
        }
        __syncthreads();                      // z4 reads done before next u writes
    }
}

// ---------- Per-channel multiplier precompute (f32, R table in LDS) ----------
// Output: Abuf[(c*2+u)*PLANE_HALF + e] = (M_{u,v=0}.re, .im, M_{u,v=1}.re, .im)
__global__ void prep_kernel(const float* __restrict__ weight,
                            const float* __restrict__ bias,
                            float4* __restrict__ Abuf)
{
    __shared__ float tabc[272], tabs[272];    // exp(-2*pi*i*t/272)
    __shared__ float Rs[69*5*4];              // (g2*5+a)*4 + {R0r,R0i,R1r,R1i}
    for (int t = threadIdx.x; t < 272; t += blockDim.x) {
        float s, c; sincosf(-2.0f*(float)PI_D*(float)t/272.0f, &s, &c);
        tabc[t] = c; tabs[t] = s;
    }
    const int c     = blockIdx.x >> 3;
    const int chunk = blockIdx.x & 7;
    const float* wp = weight + c*25;
    const float r = 1.0f/(1.0f + expf(9.0f - bias[c])) + 1e-5f;
    __syncthreads();
    // R precompute: R{0,1}[a][g2] = sum_b w[a][b] (+/-)^b e2[b](g2). 345 items.
    for (int it = threadIdx.x; it < 69*5; it += blockDim.x) {
        int g2 = it / 5, a = it - 5*g2;
        float c2 = tabc[g2], s2 = tabs[g2];
        float e2r[5], e2i[5];
        e2r[2]=1.0f; e2i[2]=0.0f; e2r[3]=c2; e2i[3]=s2;
        e2r[4]=c2*c2-s2*s2; e2i[4]=2.0f*c2*s2;
        e2r[1]=c2; e2i[1]=-s2; e2r[0]=e2r[4]; e2i[0]=-e2i[4];
        float w0=wp[a*5+0], w1=wp[a*5+1], w2=wp[a*5+2], w3=wp[a*5+3], w4=wp[a*5+4];
        float Rer = w0*e2r[0] + w2*e2r[2] + w4*e2r[4];
        float Rei = w0*e2i[0] + w2*e2i[2] + w4*e2i[4];
        float Ror = w1*e2r[1] + w3*e2r[3];
        float Roi = w1*e2i[1] + w3*e2i[3];
        Rs[it*4+0] = Rer + Ror;  Rs[it*4+1] = Rei + Roi;   // R0
        Rs[it*4+2] = Rer - Ror;  Rs[it*4+3] = Rei - Roi;   // R1
    }
    __syncthreads();

    const int e_lo = chunk * 1173;           // 8*1173 == PLANE_HALF
    const int e_hi = e_lo + 1173;
    int e  = e_lo + (int)threadIdx.x;
    int g1 = e / HC, g2 = e - (e/HC)*HC;
    for (; e < e_hi; e += blockDim.x) {
        float c1 = tabc[g1], s1 = tabs[g1];
        float e1r[5], e1i[5];
        e1r[2]=1.0f; e1i[2]=0.0f; e1r[3]=c1; e1i[3]=s1;
        e1r[4]=c1*c1-s1*s1; e1i[4]=2.0f*c1*s1;
        e1r[1]=c1; e1i[1]=-s1; e1r[0]=e1r[4]; e1i[0]=-e1i[4];

        // FB[a1][b1] = sum_a (+/-)^(a*a1) e1[a] * R[b1][a], via even/odd-a split.
        float FBr[2][2], FBi[2][2];
#pragma unroll
        for (int b1 = 0; b1 < 2; b1++) {
            float Per=0.f, Pei=0.f, Por=0.f, Poi=0.f;
#pragma unroll
            for (int a = 0; a < 5; a++) {
                float Rr = Rs[(g2*5+a)*4 + 2*b1];
                float Ri = Rs[(g2*5+a)*4 + 2*b1 + 1];
                float tr = e1r[a]*Rr - e1i[a]*Ri;
                float ti = e1r[a]*Ri + e1i[a]*Rr;
                if (a & 1) { Por += tr; Poi += ti; } else { Per += tr; Pei += ti; }
            }
            FBr[0][b1] = Per + Por;  FBi[0][b1] = Pei + Poi;
            FBr[1][b1] = Per - Por;  FBi[1][b1] = Pei - Poi;
        }
        float c2 = tabc[g2], s2 = tabs[g2];
        float ur[2]={1.0f+c1, 1.0f-c1}, ui[2]={s1, -s1};
        float vr[2]={1.0f+c2, 1.0f-c2}, vi[2]={s2, -s2};
        float Br_[2][2], Bi_[2][2];
#pragma unroll
        for (int a1 = 0; a1 < 2; a1++)
#pragma unroll
            for (int b1 = 0; b1 < 2; b1++) {
                Br_[a1][b1] = ur[a1]*vr[b1] - ui[a1]*vi[b1];
                Bi_[a1][b1] = ur[a1]*vi[b1] + ui[a1]*vr[b1];
            }
        float invW=0.f, Qr=0.f, Qi=0.f;
#pragma unroll
        for (int a1 = 0; a1 < 2; a1++)
#pragma unroll
            for (int b1 = 0; b1 < 2; b1++) {
                invW += FBr[a1][b1]*FBr[a1][b1] + FBi[a1][b1]*FBi[a1][b1];
                Qr += FBr[a1][b1]*Br_[a1][b1] - FBi[a1][b1]*Bi_[a1][b1];
                Qi += FBr[a1][b1]*Bi_[a1][b1] + FBi[a1][b1]*Br_[a1][b1];
            }
        invW *= 0.25f; Qr *= 0.25f; Qi *= 0.25f;
        float den = 1.0f/(invW + r);
        float Sr = (1.0f - Qr)*den, Si = -Qi*den;
        float Mr[2][2], Mi[2][2];
#pragma unroll
        for (int a1 = 0; a1 < 2; a1++)
#pragma unroll
            for (int b1 = 0; b1 < 2; b1++) {
                Mr[a1][b1] = Br_[a1][b1] + FBr[a1][b1]*Sr + FBi[a1][b1]*Si;
                Mi[a1][b1] = Bi_[a1][b1] + FBr[a1][b1]*Si - FBi[a1][b1]*Sr;
            }
        const float scale = 1.0f/73984.0f;   // 1/272^2 ifft normalization
#pragma unroll
        for (int uu = 0; uu < 2; uu++) {
            float ov[4];
#pragma unroll
            for (int vv = 0; vv < 2; vv++) {
                float sr=0.f, si=0.f;
#pragma unroll
                for (int a1 = 0; a1 < 2; a1++)
#pragma unroll
                    for (int b1 = 0; b1 < 2; b1++) {
                        if ((a1*uu + b1*vv) & 1) { sr -= Mr[a1][b1]; si -= Mi[a1][b1]; }
                        else                     { sr += Mr[a1][b1]; si += Mi[a1][b1]; }
                    }
                int t = g1*uu + g2*vv;                 // <= 203 < 272
                float pc = tabc[t], ps = -tabs[t];     // exp(+i*pi*t/136)
                ov[2*vv]   = (pc*sr - ps*si)*scale;
                ov[2*vv+1] = (pc*si + ps*sr)*scale;
            }
            Abuf[((size_t)(c*2 + uu))*PLANE_HALF + e] =
                make_float4(ov[0], ov[1], ov[2], ov[3]);
        }
        g1 += 3; g2 += 49; if (g2 >= HC) { g2 -= HC; g1++; }   // e += 256
    }
}

extern "C" void kernel_launch(void* const* d_in, const int* in_sizes, int n_in,
                              void* d_out, int out_size, void* d_ws, size_t ws_size,
                              hipStream_t stream)
{
    const float* x      = (const float*)d_in[0];
    const float* weight = (const float*)d_in[1];
    const float* bias   = (const float*)d_in[2];
    float* out = (float*)d_out;

    float4* Abuf = (float4*)d_ws;     // 128 * 9384 * 16B = 19.2 MB

    (void)hipFuncSetAttribute((const void*)conv_kernel,
                              hipFuncAttributeMaxDynamicSharedMemorySize,
                              (int)LDS_BYTES);

    prep_kernel<<<512, 256, 0, stream>>>(weight, bias, Abuf);
    conv_kernel<<<NPLANES, 1024, LDS_BYTES, stream>>>(x, Abuf, out);
}